// Round 10
// baseline (536.587 us; speedup 1.0000x reference)
//
#include <hip/hip_runtime.h>
#include <hip/hip_bf16.h>
#include <stdint.h>

static constexpr int Bsz = 1024;
static constexpr int TT  = 256;
static constexpr int FF  = 124;
static constexpr int HH  = 64;
static constexpr int GG  = 256;   // 4*H
static constexpr int BB  = 16;    // batch rows per block
static constexpr int C_OFF = Bsz * 8;
static constexpr int H_OFF = C_OFF + Bsz * HH;

// packed-weight workspace layout (uint16_t units)
static constexpr int WXH_U16 = 24 * 256 * 8;      // Wx/Wh frags
static constexpr int W1P_U16 = 256 * 4096;        // W1 frags, 256 blocks x 8KB
static constexpr size_t WS_NEED = (size_t)(WXH_U16 + W1P_U16) * 2;  // ~2.1 MB

// LDS pool layout (bytes)
static constexpr int XS0 = 0;        // 8 slots x 8192  (f32 xs tiles, swizzled)
static constexpr int XP0 = 65536;    // 4 slots x 16384 (f32 xproj ring)
static constexpr int HB0 = 131072;   // 2 x 2048        (bf16 h, swizzled)
static constexpr int MA0 = 135168;   // 16*65*4  (a1)
static constexpr int MB0 = 139328;   // 16*65*4  (a2)
static constexpr int POOLSZ = 143488;
// W2 staging aliases the (dead after loop) xs region at offset 0.

typedef __attribute__((ext_vector_type(8))) short bf16x8;
typedef __attribute__((ext_vector_type(4))) float f32x4;

#define MFMA16 __builtin_amdgcn_mfma_f32_16x16x32_bf16

__device__ __forceinline__ uint16_t f2bf(float x) {
  union { float f; uint32_t u; } v; v.f = x;
  return (uint16_t)((v.u + 0x7FFFu + ((v.u >> 16) & 1u)) >> 16);
}
__device__ __forceinline__ uint32_t cvtpk(float lo, float hi) {
  uint32_t r;
  asm("v_cvt_pk_bf16_f32 %0, %1, %2" : "=v"(r) : "v"(lo), "v"(hi));
  return r;
}
__device__ __forceinline__ uint16_t bf1(float x) { return (uint16_t)cvtpk(x, x); }
__device__ __forceinline__ float fsig(float x) {
  return __builtin_amdgcn_rcpf(1.0f + __builtin_amdgcn_exp2f(-1.4426950408889634f * x));
}
__device__ __forceinline__ float ftanh(float x) {
  float e = __builtin_amdgcn_exp2f(-2.8853900817779268f * x);
  return (1.0f - e) * __builtin_amdgcn_rcpf(1.0f + e);
}
__device__ __forceinline__ bf16x8 cvt8(float4 a, float4 b) {
  union { uint32_t u[4]; bf16x8 v; } r;
  r.u[0] = cvtpk(a.x, a.y); r.u[1] = cvtpk(a.z, a.w);
  r.u[2] = cvtpk(b.x, b.y); r.u[3] = cvtpk(b.z, b.w);
  return r.v;
}
__device__ __forceinline__ void dma16(const void* g, void* l) {
  __builtin_amdgcn_global_load_lds(
      (const __attribute__((address_space(1))) uint32_t*)g,
      (__attribute__((address_space(3))) uint32_t*)l, 16, 0, 0);
}

// ---------------- pre-pass: pack Wx/Wh/W1 into bf16 fragment order ----------------
__global__ __launch_bounds__(256) void pack_weights(
    const float* __restrict__ Wx, const float* __restrict__ Wh,
    const float* __restrict__ W1, uint16_t* __restrict__ wsp)
{
  const int c = blockIdx.x * 256 + threadIdx.x;
  uint16_t v[8];
  size_t dst;
  if (c < 6144) {                       // Wx/Wh frags: [f 0..23][tid 0..255][8]
    const int f = c >> 8, tid = c & 255;
    const int w = tid >> 6, l = tid & 63;
    const int kgl = (l >> 4) * 8, r16 = l & 15;
    if (f < 16) {
      const int g = f >> 2, kf = f & 3;
      const int col = g * 64 + w * 16 + r16;
#pragma unroll
      for (int j = 0; j < 8; ++j) v[j] = f2bf(Wx[(size_t)(kf * 32 + kgl + j) * GG + col]);
    } else {
      const int g = (f - 16) >> 1, kf = (f - 16) & 1;
      const int col = g * 64 + w * 16 + r16;
#pragma unroll
      for (int j = 0; j < 8; ++j) v[j] = f2bf(Wh[(size_t)(kf * 32 + kgl + j) * GG + col]);
    }
    dst = (size_t)c * 8;
  } else if (c < 6144 + 131072) {       // W1 frags: [t][w][half][l][8]
    const int cc = c - 6144;
    const int t = cc >> 9, r = cc & 511;
    const int w = r >> 7, half = (r >> 6) & 1, l = r & 63;
    const int row0 = t * 64 + half * 32 + (l >> 4) * 8;
    const int col = w * 16 + (l & 15);
#pragma unroll
    for (int j = 0; j < 8; ++j) v[j] = f2bf(W1[(size_t)(row0 + j) * 64 + col]);
    dst = (size_t)WXH_U16 + (size_t)cc * 8;
  } else return;
  uint4 pk;
  pk.x = (uint32_t)v[0] | ((uint32_t)v[1] << 16);
  pk.y = (uint32_t)v[2] | ((uint32_t)v[3] << 16);
  pk.z = (uint32_t)v[4] | ((uint32_t)v[5] << 16);
  pk.w = (uint32_t)v[6] | ((uint32_t)v[7] << 16);
  *(uint4*)(wsp + dst) = pk;
}

// ---------------- main kernel: 4 DMA producers + 8 hf-split consumers, 12 waves ----------------

// producer period body (R8-proven).  vmcnt invariant: 8 DMAs outstanding at top
// (pairs for t = PRT+2 .. PRT+5); vmcnt(6) retires the pair delivering xs(PRT+2).
#define PER_PROD(PRT, U) { \
  asm volatile("s_waitcnt vmcnt(6)" ::: "memory"); \
  const bool live_ = (PRT) + 2 < TT; \
  bf16x8 ax0, ax1, ax2, ax3; \
  if (live_) { \
    const char* xb = pool + (((U) + 2) & 7) * 8192; \
    float4 y0 = *(const float4*)(xb + offx0); \
    float4 y1 = *(const float4*)(xb + offx1); \
    float4 y2 = *(const float4*)(xb + offx2); \
    float4 y3 = *(const float4*)(xb + offx3); \
    ax0 = cvt8(y0, y1); ax1 = cvt8(y2, y3); \
    float4 y4 = *(const float4*)(xb + offx4); \
    float4 y5 = *(const float4*)(xb + offx5); \
    float4 y6 = *(const float4*)(xb + offx6); \
    float4 y7 = *(const float4*)(xb + offx7); \
    ax2 = cvt8(y4, y5); ax3 = cvt8(y6, y7); \
  } \
  { char* ld = pool + (((U) + 6) & 7) * 8192 + pw * 2048; \
    dma16(gsrc0, ld); dma16(gsrc1, ld + 1024); } \
  if ((PRT) + 7 < TT) { gsrc0 += inc0; gsrc1 += inc1; } \
  if (live_) { \
    char* xpw = pool + XP0 + (((U) + 2) & 3) * 16384 + pw * 4096 + l * 16; \
    _Pragma("unroll") \
    for (int g = 0; g < 4; ++g) { \
      f32x4 acc = {bias4[g], bias4[g], bias4[g], bias4[g]}; \
      acc = MFMA16(ax0, bwx[g][0], acc, 0, 0, 0); \
      acc = MFMA16(ax1, bwx[g][1], acc, 0, 0, 0); \
      acc = MFMA16(ax2, bwx[g][2], acc, 0, 0, 0); \
      acc = MFMA16(ax3, bwx[g][3], acc, 0, 0, 0); \
      *(f32x4*)(xpw + g * 1024) = acc; \
    } \
  } }

// consumer period body (R7-proven hf-split; W1 stream stays whole on hf0 waves).
#define PER_CONS(PRT, U) { \
  bf16x8 nw1a = {}, nw1b = {}; \
  if (hf == 0) { \
    const uint16_t* w1p = wsp + (size_t)WXH_U16 + ((size_t)(PRT) * 512 + cs * 128 + l) * 8; \
    nw1a = *(const bf16x8*)(w1p); \
    nw1b = *(const bf16x8*)(w1p + 512); \
  } \
  const char* xpb = pool + XP0 + ((U) & 3) * 16384 + cs * 4096 + l * 16; \
  f32x4 a0 = *(const f32x4*)(xpb); \
  f32x4 a1 = *(const f32x4*)(xpb + 1024); \
  f32x4 a2 = *(const f32x4*)(xpb + 2048); \
  f32x4 a3 = *(const f32x4*)(xpb + 3072); \
  const char* hb = pool + HB0 + ((U) & 1) * 2048; \
  bf16x8 ah0 = *(const bf16x8*)(hb + row16 * 128 + (((0 + kg) << 4) ^ swz)); \
  bf16x8 ah1 = *(const bf16x8*)(hb + row16 * 128 + (((4 + kg) << 4) ^ swz)); \
  a0 = MFMA16(ah0, bwh[0][0], a0, 0, 0, 0); \
  a1 = MFMA16(ah0, bwh[1][0], a1, 0, 0, 0); \
  a2 = MFMA16(ah0, bwh[2][0], a2, 0, 0, 0); \
  a3 = MFMA16(ah0, bwh[3][0], a3, 0, 0, 0); \
  a0 = MFMA16(ah1, bwh[0][1], a0, 0, 0, 0); \
  a1 = MFMA16(ah1, bwh[1][1], a1, 0, 0, 0); \
  a2 = MFMA16(ah1, bwh[2][1], a2, 0, 0, 0); \
  a3 = MFMA16(ah1, bwh[3][1], a3, 0, 0, 0); \
  if (hf == 0) { \
    wacc = MFMA16(ah0, cw1a, wacc, 0, 0, 0); \
    wacc = MFMA16(ah1, cw1b, wacc, 0, 0, 0); \
    cw1a = nw1a; cw1b = nw1b; \
  } \
  float gi0, gi1, gf0, gf1, gg0, gg1, go0, go1; \
  if (hf == 0) { \
    gi0 = a0[0]; gi1 = a0[1]; gf0 = a1[0]; gf1 = a1[1]; \
    gg0 = a2[0]; gg1 = a2[1]; go0 = a3[0]; go1 = a3[1]; \
  } else { \
    gi0 = a0[2]; gi1 = a0[3]; gf0 = a1[2]; gf1 = a1[3]; \
    gg0 = a2[2]; gg1 = a2[3]; go0 = a3[2]; go1 = a3[3]; \
  } \
  char* hw = pool + HB0 + (((U) & 1) ^ 1) * 2048; \
  { \
    float i_ = fsig(gi0), f_ = fsig(gf0), gv = ftanh(gg0), o_ = fsig(go0); \
    float cn = f_ * cacc0 + i_ * gv; \
    cacc0 = cn; \
    float hv = o_ * ftanh(cn); \
    const int row = kg * 4 + hf * 2; \
    *(uint16_t*)(hw + row * 128 + (((kcol >> 3) << 4) ^ ((row & 7) << 4)) + (kcol & 7) * 2) = bf1(hv); \
  } \
  { \
    float i_ = fsig(gi1), f_ = fsig(gf1), gv = ftanh(gg1), o_ = fsig(go1); \
    float cn = f_ * cacc1 + i_ * gv; \
    cacc1 = cn; \
    float hv = o_ * ftanh(cn); \
    const int row = kg * 4 + hf * 2 + 1; \
    *(uint16_t*)(hw + row * 128 + (((kcol >> 3) << 4) ^ ((row & 7) << 4)) + (kcol & 7) * 2) = bf1(hv); \
  } }

#define PERIOD(PRT, U) { \
  if (w < 8) { PER_CONS(PRT, U) } else { PER_PROD(PRT, U) } \
  asm volatile("s_waitcnt lgkmcnt(0)\n\ts_barrier" ::: "memory"); }

// 768 threads = 12 waves = 3 waves/EU at 1 block/CU (LDS forces 1 block/CU).
// (768, 3) -> VGPR cap 512/3 = 170 >= ~140 actual -> no spill (R8 lesson: the
// DEFAULT heuristic assumed 2 blocks/CU -> cap 84/128 -> loop-carried spill).
__global__ __launch_bounds__(768, 3)
void actor_pc(
    const float* __restrict__ x,  const float* __restrict__ pa,
    const float* __restrict__ bg, const uint16_t* __restrict__ wsp,
    const float* __restrict__ b1, const float* __restrict__ W2,
    const float* __restrict__ b2, const float* __restrict__ W3,
    const float* __restrict__ b3, float* __restrict__ out)
{
  __shared__ __align__(16) char pool[POOLSZ];

  const int tid   = threadIdx.x;
  const int w     = tid >> 6;     // 0..7 consumers, 8..11 producers
  const int cs    = w & 3;        // consumer gate-col slice / producer pw
  const int hf    = (w >> 2) & 1; // consumer row-half (meaningful for w<8)
  const int pw    = w & 3;
  const int l     = tid & 63;
  const int row16 = l & 15;
  const int kg    = l >> 4;
  const int b0    = blockIdx.x * BB;
  const int swz   = (row16 & 7) << 4;
  const int kcol  = cs * 16 + row16;

  if (w < 8) __builtin_amdgcn_s_setprio(1);

  // ---- role state ----
  bf16x8 bwx[4][4];     // producers only (loop-spanning)
  bf16x8 bwh[4][2];     // consumers only
  float  bias4[4];
  bf16x8 cw1a = {}, cw1b = {};   // hf0 consumers only
  float  cacc0 = 0.f, cacc1 = 0.f;
  f32x4  wacc = {0.f, 0.f, 0.f, 0.f};

  // producer xs-read swizzled offsets (per-lane, loop-invariant)
  int offx0, offx1, offx2, offx3, offx4, offx5, offx6, offx7;
  {
    const int rb = row16 * 512, r7 = row16 & 7;
#define OX(kf, lh) (rb + ((((kf) * 8 + kg * 2 + (lh)) ^ r7) << 4))
    offx0 = OX(0, 0); offx1 = OX(0, 1); offx2 = OX(1, 0); offx3 = OX(1, 1);
    offx4 = OX(2, 0); offx5 = OX(2, 1); offx6 = OX(3, 0); offx7 = OX(3, 1);
#undef OX
  }
  // producer DMA source pointers (per-lane swizzled global addresses)
  const char* gsrc0; const char* gsrc1; int inc0 = 0, inc1 = 0;
  {
#define GSRC(j, G, INC) { \
    const int d = pw * 2 + (j); \
    const int row = d * 2 + (l >> 5); \
    const int c_swz = l & 31; \
    const int c_or = c_swz ^ (row & 7); \
    const size_t rb_ = (size_t)(b0 + row) * TT; \
    if (c_or == 31) { G = (const char*)(pa + rb_ * 4); INC = 16; } \
    else { G = (const char*)(x + rb_ * FF + c_or * 4); INC = FF * 4; } }
    GSRC(0, gsrc0, inc0)
    GSRC(1, gsrc1, inc1)
#undef GSRC
  }

  if (w >= 8) {
#pragma unroll
    for (int g = 0; g < 4; ++g) {
#pragma unroll
      for (int kf = 0; kf < 4; ++kf)
        bwx[g][kf] = *(const bf16x8*)(wsp + ((size_t)(g * 4 + kf) * 256 + pw * 64 + l) * 8);
      bias4[g] = bg[g * 64 + pw * 16 + row16];
    }
    // prologue DMAs: xs(0..5) into slots 0..5
#pragma unroll
    for (int s = 0; s < 6; ++s) {
      char* ld = pool + s * 8192 + pw * 2048;
      dma16(gsrc0, ld); dma16(gsrc1, ld + 1024);
      gsrc0 += inc0; gsrc1 += inc1;   // ends at t = 6
    }
  } else {
#pragma unroll
    for (int g = 0; g < 4; ++g)
#pragma unroll
      for (int kf = 0; kf < 2; ++kf)
        bwh[g][kf] = *(const bf16x8*)(wsp + ((size_t)(16 + g * 2 + kf) * 256 + cs * 64 + l) * 8);
    if (hf == 0) {
      const uint16_t* w1p = wsp + (size_t)WXH_U16 + ((size_t)cs * 128 + l) * 8;  // block 0
      cw1a = *(const bf16x8*)(w1p);
      cw1b = *(const bf16x8*)(w1p + 512);
    }
  }
  if (tid < 256) ((uint64_t*)(pool + HB0))[tid] = 0ull;   // h_{-1} = 0 (parity 0)

  // ---- pre-periods: xproj(0) -> xp slot 0, xproj(1) -> xp slot 1 ----
#define PRE(TSTEP, VMC) \
  if (w >= 8) { \
    asm volatile("s_waitcnt vmcnt(" #VMC ")" ::: "memory"); \
    const char* xb = pool + (TSTEP) * 8192; \
    float4 y0 = *(const float4*)(xb + offx0), y1 = *(const float4*)(xb + offx1); \
    float4 y2 = *(const float4*)(xb + offx2), y3 = *(const float4*)(xb + offx3); \
    float4 y4 = *(const float4*)(xb + offx4), y5 = *(const float4*)(xb + offx5); \
    float4 y6 = *(const float4*)(xb + offx6), y7 = *(const float4*)(xb + offx7); \
    bf16x8 ax0 = cvt8(y0, y1), ax1 = cvt8(y2, y3), ax2 = cvt8(y4, y5), ax3 = cvt8(y6, y7); \
    char* xpw = pool + XP0 + (TSTEP) * 16384 + pw * 4096 + l * 16; \
    _Pragma("unroll") \
    for (int g = 0; g < 4; ++g) { \
      f32x4 acc = {bias4[g], bias4[g], bias4[g], bias4[g]}; \
      acc = MFMA16(ax0, bwx[g][0], acc, 0, 0, 0); \
      acc = MFMA16(ax1, bwx[g][1], acc, 0, 0, 0); \
      acc = MFMA16(ax2, bwx[g][2], acc, 0, 0, 0); \
      acc = MFMA16(ax3, bwx[g][3], acc, 0, 0, 0); \
      *(f32x4*)(xpw + g * 1024) = acc; \
    } \
  } \
  asm volatile("s_waitcnt lgkmcnt(0)\n\ts_barrier" ::: "memory");

  PRE(0, 10)
  PRE(1, 8)
#undef PRE

  // ---- main loop: 256 periods, unrolled x8 (all ring indices are immediates) ----
#pragma unroll 1
  for (int pp = 0; pp < TT; pp += 8) {
    PERIOD(pp + 0, 0) PERIOD(pp + 1, 1) PERIOD(pp + 2, 2) PERIOD(pp + 3, 3)
    PERIOD(pp + 4, 4) PERIOD(pp + 5, 5) PERIOD(pp + 6, 6) PERIOD(pp + 7, 7)
  }

  __syncthreads();   // full drain (incl. in-flight DMAs) before aliasing xs as W2

  // stage W2 into the dead xs region
  {
    float* w2l = (float*)pool;
    for (int i = tid; i < 4096; i += 768) w2l[i] = W2[i];
  }

  if (w < 8) {
    // final c/h outputs for this wave's 2 rows (h(255) is in parity-0 hbuf)
    const char* hb = pool + HB0;
#pragma unroll
    for (int jj = 0; jj < 2; ++jj) {
      const int row = kg * 4 + hf * 2 + jj;
      out[C_OFF + (size_t)(b0 + row) * HH + kcol] = (jj == 0) ? cacc0 : cacc1;
      uint32_t hu = *(const uint16_t*)(hb + row * 128 +
                    (((kcol >> 3) << 4) ^ ((row & 7) << 4)) + (kcol & 7) * 2);
      union { uint32_t u; float f; } cvt_; cvt_.u = hu << 16;
      out[H_OFF + (size_t)(b0 + row) * HH + kcol] = cvt_.f;
    }
  }
  if (w < 4) {
    // W1 tail (hf0 waves hold the full wacc): wacc += h(255) x W1block(255)
    const char* hb = pool + HB0;
    bf16x8 at0 = *(const bf16x8*)(hb + row16 * 128 + (((0 + kg) << 4) ^ swz));
    bf16x8 at1 = *(const bf16x8*)(hb + row16 * 128 + (((4 + kg) << 4) ^ swz));
    wacc = MFMA16(at0, cw1a, wacc, 0, 0, 0);
    wacc = MFMA16(at1, cw1b, wacc, 0, 0, 0);
    const float bv = b1[kcol];
    float* mlpa = (float*)(pool + MA0);
#pragma unroll
    for (int jj = 0; jj < 4; ++jj)
      mlpa[(kg * 4 + jj) * 65 + kcol] = fmaxf(wacc[jj] + bv, 0.f);
  }
  __syncthreads();
  if (tid < 512) {  // MLP layer 2: 16x64 outputs, MA0 -> MB0
    const float* mlpa = (const float*)(pool + MA0);
    const float* w2l  = (const float*)pool;
    float* mlpb = (float*)(pool + MB0);
    const int b = tid >> 5, j0 = tid & 31;
    float s0 = b2[j0], s1 = b2[j0 + 32];
#pragma unroll 8
    for (int k = 0; k < 64; ++k) {
      const float av = mlpa[b * 65 + k];
      s0 += av * w2l[k * 64 + j0];
      s1 += av * w2l[k * 64 + j0 + 32];
    }
    mlpb[b * 65 + j0]      = fmaxf(s0, 0.f);
    mlpb[b * 65 + j0 + 32] = fmaxf(s1, 0.f);
  }
  __syncthreads();
  if (tid < 128) {  // MLP layer 3: 16x8 outputs
    const float* mlpb = (const float*)(pool + MB0);
    const int b = tid >> 3, jj = tid & 7;
    float s = b3[jj];
#pragma unroll 8
    for (int k = 0; k < 64; ++k) s += mlpb[b * 65 + k] * W3[(size_t)k * 8 + jj];
    out[(size_t)(b0 + b) * 8 + jj] = s;
  }
}

// ---------------- fallback (R2 kernel, used only if ws_size too small) ----------------
__global__ __launch_bounds__(256, 1) void actor_fused_fb(
    const float* __restrict__ x,  const float* __restrict__ pa,
    const float* __restrict__ Wx, const float* __restrict__ Wh,
    const float* __restrict__ bg, const float* __restrict__ W1,
    const float* __restrict__ b1, const float* __restrict__ W2,
    const float* __restrict__ b2, const float* __restrict__ W3,
    const float* __restrict__ b3, float* __restrict__ out)
{
  __shared__ __align__(16) uint16_t xs_lds[2][BB * 128];
  __shared__ __align__(16) uint16_t h_lds[2][BB * HH];
  __shared__ float w2_lds[64 * 64];
  __shared__ float mlp_a[BB * 65];
  __shared__ float mlp_b[BB * 65];

  const int tid = threadIdx.x, w = tid >> 6, l = tid & 63;
  const int row16 = l & 15, kg = l >> 4;
  const int b0 = blockIdx.x * BB, swz = (row16 & 7) << 4;

  bf16x8 bwx[4][4], bwh[4][2];
  float bias4[4];
#pragma unroll
  for (int g = 0; g < 4; ++g) {
    const int col = g * 64 + w * 16 + row16;
    bias4[g] = bg[col];
#pragma unroll
    for (int kf = 0; kf < 4; ++kf)
#pragma unroll
      for (int j = 0; j < 8; ++j)
        bwx[g][kf][j] = (short)f2bf(Wx[(size_t)(kf * 32 + kg * 8 + j) * GG + col]);
#pragma unroll
    for (int kf = 0; kf < 2; ++kf)
#pragma unroll
      for (int j = 0; j < 8; ++j)
        bwh[g][kf][j] = (short)f2bf(Wh[(size_t)(kf * 32 + kg * 8 + j) * GG + col]);
  }
  for (int i = tid; i < 64 * 64; i += 256) w2_lds[i] = W2[i];
  reinterpret_cast<uint64_t*>(&h_lds[0][0])[tid] = 0ull;

  const int srow = tid >> 4, li = tid & 15;
  const int st_byte = srow * 256 + ((li << 4) ^ ((srow & 7) << 4));
  {
    const size_t base = (size_t)(b0 + srow) * TT + 0;
    float4 fa, fb;
    if (li < 15) { fa = *(const float4*)(x + base * FF + li * 8);
                   fb = *(const float4*)(x + base * FF + li * 8 + 4); }
    else         { fa = *(const float4*)(x + base * FF + 120);
                   fb = *(const float4*)(pa + base * 4); }
    uint4 pk;
    pk.x = (uint32_t)f2bf(fa.x) | ((uint32_t)f2bf(fa.y) << 16);
    pk.y = (uint32_t)f2bf(fa.z) | ((uint32_t)f2bf(fa.w) << 16);
    pk.z = (uint32_t)f2bf(fb.x) | ((uint32_t)f2bf(fb.y) << 16);
    pk.w = (uint32_t)f2bf(fb.z) | ((uint32_t)f2bf(fb.w) << 16);
    *(uint4*)((char*)&xs_lds[0][0] + st_byte) = pk;
  }
  float4 pfa, pfb;
  {
    const size_t base = (size_t)(b0 + srow) * TT + 1;
    if (li < 15) { pfa = *(const float4*)(x + base * FF + li * 8);
                   pfb = *(const float4*)(x + base * FF + li * 8 + 4); }
    else         { pfa = *(const float4*)(x + base * FF + 120);
                   pfb = *(const float4*)(pa + base * 4); }
  }
  __syncthreads();

  f32x4 cacc = {0.f, 0.f, 0.f, 0.f};
  f32x4 wacc = {0.f, 0.f, 0.f, 0.f};
  int cur = 0;

  for (int t = 0; t < TT; ++t) {
    {
      uint4 pk;
      pk.x = (uint32_t)f2bf(pfa.x) | ((uint32_t)f2bf(pfa.y) << 16);
      pk.y = (uint32_t)f2bf(pfa.z) | ((uint32_t)f2bf(pfa.w) << 16);
      pk.z = (uint32_t)f2bf(pfb.x) | ((uint32_t)f2bf(pfb.y) << 16);
      pk.w = (uint32_t)f2bf(pfb.z) | ((uint32_t)f2bf(pfb.w) << 16);
      *(uint4*)((char*)&xs_lds[cur ^ 1][0] + st_byte) = pk;
    }
    {
      const int tp = (t + 2 < TT) ? (t + 2) : (TT - 1);
      const size_t base = (size_t)(b0 + srow) * TT + tp;
      if (li < 15) { pfa = *(const float4*)(x + base * FF + li * 8);
                     pfb = *(const float4*)(x + base * FF + li * 8 + 4); }
      else         { pfa = *(const float4*)(x + base * FF + 120);
                     pfb = *(const float4*)(pa + base * 4); }
    }
    bf16x8 bw1a, bw1b;
    if (t > 0) {
      const size_t r0 = (size_t)(t - 1) * 64 + kg * 8;
      const int c1w = w * 16 + row16;
#pragma unroll
      for (int j = 0; j < 8; ++j) {
        bw1a[j] = (short)f2bf(W1[(r0 + j) * 64 + c1w]);
        bw1b[j] = (short)f2bf(W1[(r0 + 32 + j) * 64 + c1w]);
      }
    }
    const char* xb = (const char*)&xs_lds[cur][0];
    const char* hb = (const char*)&h_lds[cur][0];
    bf16x8 ax0 = *(const bf16x8*)(xb + row16 * 256 + (((0 * 4 + kg) << 4) ^ swz));
    bf16x8 ax1 = *(const bf16x8*)(xb + row16 * 256 + (((1 * 4 + kg) << 4) ^ swz));
    bf16x8 ax2 = *(const bf16x8*)(xb + row16 * 256 + (((2 * 4 + kg) << 4) ^ swz));
    bf16x8 ax3 = *(const bf16x8*)(xb + row16 * 256 + (((3 * 4 + kg) << 4) ^ swz));
    bf16x8 ah0 = *(const bf16x8*)(hb + row16 * 128 + (((0 + kg) << 4) ^ swz));
    bf16x8 ah1 = *(const bf16x8*)(hb + row16 * 128 + (((4 + kg) << 4) ^ swz));

    f32x4 g0 = {bias4[0], bias4[0], bias4[0], bias4[0]};
    f32x4 g1 = {bias4[1], bias4[1], bias4[1], bias4[1]};
    f32x4 g2 = {bias4[2], bias4[2], bias4[2], bias4[2]};
    f32x4 g3 = {bias4[3], bias4[3], bias4[3], bias4[3]};
    g0 = MFMA16(ax0, bwx[0][0], g0, 0, 0, 0);
    g1 = MFMA16(ax0, bwx[1][0], g1, 0, 0, 0);
    g2 = MFMA16(ax0, bwx[2][0], g2, 0, 0, 0);
    g3 = MFMA16(ax0, bwx[3][0], g3, 0, 0, 0);
    g0 = MFMA16(ax1, bwx[0][1], g0, 0, 0, 0);
    g1 = MFMA16(ax1, bwx[1][1], g1, 0, 0, 0);
    g2 = MFMA16(ax1, bwx[2][1], g2, 0, 0, 0);
    g3 = MFMA16(ax1, bwx[3][1], g3, 0, 0, 0);
    g0 = MFMA16(ax2, bwx[0][2], g0, 0, 0, 0);
    g1 = MFMA16(ax2, bwx[1][2], g1, 0, 0, 0);
    g2 = MFMA16(ax2, bwx[2][2], g2, 0, 0, 0);
    g3 = MFMA16(ax2, bwx[3][2], g3, 0, 0, 0);
    g0 = MFMA16(ax3, bwx[0][3], g0, 0, 0, 0);
    g1 = MFMA16(ax3, bwx[1][3], g1, 0, 0, 0);
    g2 = MFMA16(ax3, bwx[2][3], g2, 0, 0, 0);
    g3 = MFMA16(ax3, bwx[3][3], g3, 0, 0, 0);
    g0 = MFMA16(ah0, bwh[0][0], g0, 0, 0, 0);
    g1 = MFMA16(ah0, bwh[1][0], g1, 0, 0, 0);
    g2 = MFMA16(ah0, bwh[2][0], g2, 0, 0, 0);
    g3 = MFMA16(ah0, bwh[3][0], g3, 0, 0, 0);
    g0 = MFMA16(ah1, bwh[0][1], g0, 0, 0, 0);
    g1 = MFMA16(ah1, bwh[1][1], g1, 0, 0, 0);
    g2 = MFMA16(ah1, bwh[2][1], g2, 0, 0, 0);
    g3 = MFMA16(ah1, bwh[3][1], g3, 0, 0, 0);
    if (t > 0) {
      wacc = MFMA16(ah0, bw1a, wacc, 0, 0, 0);
      wacc = MFMA16(ah1, bw1b, wacc, 0, 0, 0);
    }
    const int kcol = w * 16 + row16;
#pragma unroll
    for (int jj = 0; jj < 4; ++jj) {
      float i_ = fsig(g0[jj]);
      float f_ = fsig(g1[jj]);
      float gv = ftanh(g2[jj]);
      float o_ = fsig(g3[jj]);
      float cn = f_ * cacc[jj] + i_ * gv;
      cacc[jj] = cn;
      float hv = o_ * ftanh(cn);
      const int row = kg * 4 + jj;
      *(uint16_t*)((char*)&h_lds[cur ^ 1][0] + row * 128 +
                   (((kcol >> 3) << 4) ^ ((row & 7) << 4)) + (kcol & 7) * 2) = f2bf(hv);
      if (t == TT - 1) {
        out[C_OFF + (size_t)(b0 + row) * HH + kcol] = cn;
        out[H_OFF + (size_t)(b0 + row) * HH + kcol] = hv;
      }
    }
    __syncthreads();
    cur ^= 1;
  }
  {
    const char* hb = (const char*)&h_lds[cur][0];
    bf16x8 at0 = *(const bf16x8*)(hb + row16 * 128 + (((0 + kg) << 4) ^ swz));
    bf16x8 at1 = *(const bf16x8*)(hb + row16 * 128 + (((4 + kg) << 4) ^ swz));
    bf16x8 bw1a, bw1b;
    const size_t r0 = (size_t)(TT - 1) * 64 + kg * 8;
    const int c1w = w * 16 + row16;
#pragma unroll
    for (int j = 0; j < 8; ++j) {
      bw1a[j] = (short)f2bf(W1[(r0 + j) * 64 + c1w]);
      bw1b[j] = (short)f2bf(W1[(r0 + 32 + j) * 64 + c1w]);
    }
    wacc = MFMA16(at0, bw1a, wacc, 0, 0, 0);
    wacc = MFMA16(at1, bw1b, wacc, 0, 0, 0);
  }
  {
    const int kcol = w * 16 + row16;
    const float bv = b1[kcol];
#pragma unroll
    for (int jj = 0; jj < 4; ++jj)
      mlp_a[(kg * 4 + jj) * 65 + kcol] = fmaxf(wacc[jj] + bv, 0.f);
  }
  __syncthreads();
  {
    const int b = tid >> 4, j0 = tid & 15;
    float s0 = b2[j0], s1 = b2[j0 + 16], s2 = b2[j0 + 32], s3 = b2[j0 + 48];
#pragma unroll 8
    for (int k = 0; k < 64; ++k) {
      const float av = mlp_a[b * 65 + k];
      s0 += av * w2_lds[k * 64 + j0];
      s1 += av * w2_lds[k * 64 + j0 + 16];
      s2 += av * w2_lds[k * 64 + j0 + 32];
      s3 += av * w2_lds[k * 64 + j0 + 48];
    }
    mlp_b[b * 65 + j0]      = fmaxf(s0, 0.f);
    mlp_b[b * 65 + j0 + 16] = fmaxf(s1, 0.f);
    mlp_b[b * 65 + j0 + 32] = fmaxf(s2, 0.f);
    mlp_b[b * 65 + j0 + 48] = fmaxf(s3, 0.f);
  }
  __syncthreads();
  if (tid < 128) {
    const int b = tid >> 3, jj = tid & 7;
    float s = b3[jj];
#pragma unroll 8
    for (int k = 0; k < 64; ++k) s += mlp_b[b * 65 + k] * W3[(size_t)k * 8 + jj];
    out[(size_t)(b0 + b) * 8 + jj] = s;
  }
}

extern "C" void kernel_launch(void* const* d_in, const int* in_sizes, int n_in,
                              void* d_out, int out_size, void* d_ws, size_t ws_size,
                              hipStream_t stream) {
  const float* x  = (const float*)d_in[0];
  const float* pa = (const float*)d_in[1];
  const float* Wx = (const float*)d_in[2];
  const float* Wh = (const float*)d_in[3];
  const float* bg = (const float*)d_in[4];
  const float* W1 = (const float*)d_in[5];
  const float* b1 = (const float*)d_in[6];
  const float* W2 = (const float*)d_in[7];
  const float* b2 = (const float*)d_in[8];
  const float* W3 = (const float*)d_in[9];
  const float* b3 = (const float*)d_in[10];
  (void)in_sizes; (void)n_in; (void)out_size;

  if (ws_size >= WS_NEED) {
    uint16_t* wsp = (uint16_t*)d_ws;
    pack_weights<<<dim3(536), dim3(256), 0, stream>>>(Wx, Wh, W1, wsp);
    actor_pc<<<dim3(Bsz / BB), dim3(768), 0, stream>>>(
        x, pa, bg, wsp, b1, W2, b2, W3, b3, (float*)d_out);
  } else {
    actor_fused_fb<<<dim3(Bsz / BB), dim3(256), 0, stream>>>(
        x, pa, Wx, Wh, bg, W1, b1, W2, b2, W3, b3, (float*)d_out);
  }
}

// Round 11
// 210.032 us; speedup vs baseline: 2.5548x; 2.5548x over previous
//
#include <hip/hip_runtime.h>
#include <hip/hip_bf16.h>
#include <stdint.h>

static constexpr int Bsz = 1024;
static constexpr int TT  = 256;
static constexpr int FF  = 124;
static constexpr int HH  = 64;
static constexpr int GG  = 256;   // 4*H
static constexpr int BB  = 16;    // batch rows per block
static constexpr int C_OFF = Bsz * 8;
static constexpr int H_OFF = C_OFF + Bsz * HH;

// packed-weight workspace layout (uint16_t units)
static constexpr int WXH_U16 = 24 * 256 * 8;      // Wx/Wh frags
static constexpr int W1P_U16 = 256 * 4096;        // W1 frags, 256 blocks x 8KB
static constexpr size_t WS_NEED = (size_t)(WXH_U16 + W1P_U16) * 2;  // ~2.1 MB

// LDS pool layout (bytes)
static constexpr int XS0  = 0;        // 8 slots x 8192  (f32 xs tiles, swizzled)
static constexpr int W1R0 = 65536;    // 4 slots x 8192  (bf16 W1 frag blocks)
static constexpr int HB0  = 98304;    // 2 x 2048        (bf16 h, swizzled)
static constexpr int MA0  = 102400;   // 16*65*4
static constexpr int MB0  = 106560;   // 16*65*4
static constexpr int POOLSZ = 110720;
// W2 staging aliases the (dead after loop) xs region at offset 0.

typedef __attribute__((ext_vector_type(8))) short bf16x8;
typedef __attribute__((ext_vector_type(4))) float f32x4;

#define MFMA16 __builtin_amdgcn_mfma_f32_16x16x32_bf16

__device__ __forceinline__ uint16_t f2bf(float x) {
  union { float f; uint32_t u; } v; v.f = x;
  return (uint16_t)((v.u + 0x7FFFu + ((v.u >> 16) & 1u)) >> 16);
}
__device__ __forceinline__ uint32_t cvtpk(float lo, float hi) {
  uint32_t r;
  asm("v_cvt_pk_bf16_f32 %0, %1, %2" : "=v"(r) : "v"(lo), "v"(hi));
  return r;
}
__device__ __forceinline__ uint16_t bf1(float x) { return (uint16_t)cvtpk(x, x); }
__device__ __forceinline__ float fsig(float x) {
  return __builtin_amdgcn_rcpf(1.0f + __builtin_amdgcn_exp2f(-1.4426950408889634f * x));
}
__device__ __forceinline__ float ftanh(float x) {
  float e = __builtin_amdgcn_exp2f(-2.8853900817779268f * x);
  return (1.0f - e) * __builtin_amdgcn_rcpf(1.0f + e);
}
__device__ __forceinline__ bf16x8 cvt8(float4 a, float4 b) {
  union { uint32_t u[4]; bf16x8 v; } r;
  r.u[0] = cvtpk(a.x, a.y); r.u[1] = cvtpk(a.z, a.w);
  r.u[2] = cvtpk(b.x, b.y); r.u[3] = cvtpk(b.z, b.w);
  return r.v;
}
__device__ __forceinline__ void dma16(const void* g, void* l) {
  __builtin_amdgcn_global_load_lds(
      (const __attribute__((address_space(1))) uint32_t*)g,
      (__attribute__((address_space(3))) uint32_t*)l, 16, 0, 0);
}

// ---------------- pre-pass: pack Wx/Wh/W1 into bf16 fragment order ----------------
__global__ __launch_bounds__(256) void pack_weights(
    const float* __restrict__ Wx, const float* __restrict__ Wh,
    const float* __restrict__ W1, uint16_t* __restrict__ wsp)
{
  const int c = blockIdx.x * 256 + threadIdx.x;
  uint16_t v[8];
  size_t dst;
  if (c < 6144) {                       // Wx/Wh frags: [f 0..23][tid 0..255][8]
    const int f = c >> 8, tid = c & 255;
    const int w = tid >> 6, l = tid & 63;
    const int kgl = (l >> 4) * 8, r16 = l & 15;
    if (f < 16) {
      const int g = f >> 2, kf = f & 3;
      const int col = g * 64 + w * 16 + r16;
#pragma unroll
      for (int j = 0; j < 8; ++j) v[j] = f2bf(Wx[(size_t)(kf * 32 + kgl + j) * GG + col]);
    } else {
      const int g = (f - 16) >> 1, kf = (f - 16) & 1;
      const int col = g * 64 + w * 16 + r16;
#pragma unroll
      for (int j = 0; j < 8; ++j) v[j] = f2bf(Wh[(size_t)(kf * 32 + kgl + j) * GG + col]);
    }
    dst = (size_t)c * 8;
  } else if (c < 6144 + 131072) {       // W1 frags: [t][w][half][l][8]
    const int cc = c - 6144;
    const int t = cc >> 9, r = cc & 511;
    const int w = r >> 7, half = (r >> 6) & 1, l = r & 63;
    const int row0 = t * 64 + half * 32 + (l >> 4) * 8;
    const int col = w * 16 + (l & 15);
#pragma unroll
    for (int j = 0; j < 8; ++j) v[j] = f2bf(W1[(size_t)(row0 + j) * 64 + col]);
    dst = (size_t)WXH_U16 + (size_t)cc * 8;
  } else return;
  uint4 pk;
  pk.x = (uint32_t)v[0] | ((uint32_t)v[1] << 16);
  pk.y = (uint32_t)v[2] | ((uint32_t)v[3] << 16);
  pk.z = (uint32_t)v[4] | ((uint32_t)v[5] << 16);
  pk.w = (uint32_t)v[6] | ((uint32_t)v[7] << 16);
  *(uint4*)(wsp + dst) = pk;
}

// ---------------- main kernel: 4 merged waves (xproj in regs, W1 via LDS DMA) ----------------
// Per-period vmem issue order (per wave): [W1(t+2) x2, xs(t+4) x2].
// Invariant: top-of-period-t `vmcnt(4)` completes W1(t) and xs(t+2) (each issued
// at t-2); readers touch them at t+1 -> one barrier after the owner's completing
// wait -> formally race-free cross-wave.  Period t: uses xproj(t) from XPU regs,
// recurrence with h(t-1) & W1(t-1) (LDS), computes xproj(t+1) into XPN regs.
#define PERIOD(PRT, XPU, XPN) { \
  asm volatile("s_waitcnt vmcnt(4)" ::: "memory"); \
  const char* hb = pool + HB0 + ((PRT) & 1) * 2048; \
  bf16x8 ah0 = *(const bf16x8*)(hb + row16 * 128 + (((0 + kg) << 4) ^ swz)); \
  bf16x8 ah1 = *(const bf16x8*)(hb + row16 * 128 + (((4 + kg) << 4) ^ swz)); \
  const char* wbp = pool + W1R0 + (((PRT) + 3) & 3) * 8192 + w * 2048 + l * 16; \
  bf16x8 bw1a = *(const bf16x8*)(wbp); \
  bf16x8 bw1b = *(const bf16x8*)(wbp + 1024); \
  f32x4 a0 = XPU[0], a1 = XPU[1], a2 = XPU[2], a3 = XPU[3]; \
  a0 = MFMA16(ah0, bwh[0][0], a0, 0, 0, 0); \
  a1 = MFMA16(ah0, bwh[1][0], a1, 0, 0, 0); \
  a2 = MFMA16(ah0, bwh[2][0], a2, 0, 0, 0); \
  a3 = MFMA16(ah0, bwh[3][0], a3, 0, 0, 0); \
  a0 = MFMA16(ah1, bwh[0][1], a0, 0, 0, 0); \
  a1 = MFMA16(ah1, bwh[1][1], a1, 0, 0, 0); \
  a2 = MFMA16(ah1, bwh[2][1], a2, 0, 0, 0); \
  a3 = MFMA16(ah1, bwh[3][1], a3, 0, 0, 0); \
  wacc = MFMA16(ah0, bw1a, wacc, 0, 0, 0); \
  wacc = MFMA16(ah1, bw1b, wacc, 0, 0, 0); \
  if ((PRT) + 1 < TT) { \
    const char* xb = pool + (((PRT) + 1) & 7) * 8192; \
    float4 y0 = *(const float4*)(xb + offx0); \
    float4 y1 = *(const float4*)(xb + offx1); \
    float4 y2 = *(const float4*)(xb + offx2); \
    float4 y3 = *(const float4*)(xb + offx3); \
    float4 y4 = *(const float4*)(xb + offx4); \
    float4 y5 = *(const float4*)(xb + offx5); \
    float4 y6 = *(const float4*)(xb + offx6); \
    float4 y7 = *(const float4*)(xb + offx7); \
    bf16x8 ax0 = cvt8(y0, y1), ax1 = cvt8(y2, y3); \
    bf16x8 ax2 = cvt8(y4, y5), ax3 = cvt8(y6, y7); \
    _Pragma("unroll") \
    for (int g = 0; g < 4; ++g) { \
      f32x4 accg = {bias4[g], bias4[g], bias4[g], bias4[g]}; \
      accg = MFMA16(ax0, bwx[g][0], accg, 0, 0, 0); \
      accg = MFMA16(ax1, bwx[g][1], accg, 0, 0, 0); \
      accg = MFMA16(ax2, bwx[g][2], accg, 0, 0, 0); \
      accg = MFMA16(ax3, bwx[g][3], accg, 0, 0, 0); \
      XPN[g] = accg; \
    } \
  } \
  { const int wb_ = ((PRT) + 2 < TT) ? (PRT) + 2 : TT - 1; \
    const char* gs = w1g + (size_t)wb_ * 8192 + w * 2048 + l * 16; \
    char* ld = pool + W1R0 + (((PRT) + 2) & 3) * 8192 + w * 2048; \
    dma16(gs, ld); dma16(gs + 1024, ld + 1024); } \
  { char* ld = pool + (((PRT) + 4) & 7) * 8192 + w * 2048; \
    dma16(gsrc0, ld); dma16(gsrc1, ld + 1024); \
    if ((PRT) + 5 < TT) { gsrc0 += inc0; gsrc1 += inc1; } } \
  char* hw = pool + HB0 + (((PRT) & 1) ^ 1) * 2048; \
  _Pragma("unroll") \
  for (int jj = 0; jj < 4; ++jj) { \
    float i_ = fsig(a0[jj]); \
    float f_ = fsig(a1[jj]); \
    float gv = ftanh(a2[jj]); \
    float o_ = fsig(a3[jj]); \
    float cn = f_ * cacc[jj] + i_ * gv; \
    cacc[jj] = cn; \
    float hv = o_ * ftanh(cn); \
    const int row = kg * 4 + jj; \
    *(uint16_t*)(hw + row * 128 + (((kcol >> 3) << 4) ^ ((row & 7) << 4)) + (kcol & 7) * 2) = bf1(hv); \
  } \
  asm volatile("s_waitcnt lgkmcnt(0)\n\ts_barrier" ::: "memory"); }

// 256 threads = 4 waves = 1 wave/EU; (256,1) -> VGPR cap 512 -> no spill possible.
__global__ __launch_bounds__(256, 1)
void actor_merged(
    const float* __restrict__ x,  const float* __restrict__ pa,
    const float* __restrict__ bg, const uint16_t* __restrict__ wsp,
    const float* __restrict__ b1, const float* __restrict__ W2,
    const float* __restrict__ b2, const float* __restrict__ W3,
    const float* __restrict__ b3, float* __restrict__ out)
{
  __shared__ __align__(16) char pool[POOLSZ];

  const int tid   = threadIdx.x;
  const int w     = tid >> 6;     // wave 0..3 == gate-col slice
  const int l     = tid & 63;
  const int row16 = l & 15;
  const int kg    = l >> 4;
  const int b0    = blockIdx.x * BB;
  const int swz   = (row16 & 7) << 4;
  const int kcol  = w * 16 + row16;
  const char* w1g = (const char*)(wsp + WXH_U16);

  // ---- persistent state ----
  bf16x8 bwx[4][4];   // Wx frags (this wave's gate-col slice, all K)
  bf16x8 bwh[4][2];   // Wh frags
  float  bias4[4];
  float  cacc[4] = {0.f, 0.f, 0.f, 0.f};
  f32x4  wacc = {0.f, 0.f, 0.f, 0.f};
  f32x4  XPA[4], XPB[4];   // xproj double buffer (registers)

  // xs-read swizzled offsets (per-lane, loop-invariant)
  int offx0, offx1, offx2, offx3, offx4, offx5, offx6, offx7;
  {
    const int rb = row16 * 512, r7 = row16 & 7;
#define OX(kf, lh) (rb + ((((kf) * 8 + kg * 2 + (lh)) ^ r7) << 4))
    offx0 = OX(0, 0); offx1 = OX(0, 1); offx2 = OX(1, 0); offx3 = OX(1, 1);
    offx4 = OX(2, 0); offx5 = OX(2, 1); offx6 = OX(3, 0); offx7 = OX(3, 1);
#undef OX
  }
  // xs DMA source pointers (per-lane swizzled global addresses), R8-proven (pw = w)
  const char* gsrc0; const char* gsrc1; int inc0 = 0, inc1 = 0;
  {
#define GSRC(j, G, INC) { \
    const int d = w * 2 + (j); \
    const int row = d * 2 + (l >> 5); \
    const int c_swz = l & 31; \
    const int c_or = c_swz ^ (row & 7); \
    const size_t rb_ = (size_t)(b0 + row) * TT; \
    if (c_or == 31) { G = (const char*)(pa + rb_ * 4); INC = 16; } \
    else { G = (const char*)(x + rb_ * FF + c_or * 4); INC = FF * 4; } }
    GSRC(0, gsrc0, inc0)
    GSRC(1, gsrc1, inc1)
#undef GSRC
  }

  // weight fragments (all waves)
#pragma unroll
  for (int g = 0; g < 4; ++g) {
#pragma unroll
    for (int kf = 0; kf < 4; ++kf)
      bwx[g][kf] = *(const bf16x8*)(wsp + ((size_t)(g * 4 + kf) * 256 + w * 64 + l) * 8);
#pragma unroll
    for (int kf = 0; kf < 2; ++kf)
      bwh[g][kf] = *(const bf16x8*)(wsp + ((size_t)(16 + g * 2 + kf) * 256 + w * 64 + l) * 8);
    bias4[g] = bg[g * 64 + w * 16 + row16];
  }
  ((uint64_t*)(pool + HB0))[tid] = 0ull;   // h_{-1} = 0 (parity 0; 256*8 = 2048 B)

  // ---- prologue DMAs, exact order (14 per wave) ----
  {
    const char* gsW = w1g + w * 2048 + l * 16;          // W1 block 0 source
    // 1-2: W1(0)-content -> slot 3 (dummy for t=0 read; x0 multiplies h(-1)=0)
    { char* ld = pool + W1R0 + 3 * 8192 + w * 2048; dma16(gsW, ld); dma16(gsW + 1024, ld + 1024); }
    // 3-4: xs(0) -> slot 0
    { char* ld = pool + 0 * 8192 + w * 2048; dma16(gsrc0, ld); dma16(gsrc1, ld + 1024); gsrc0 += inc0; gsrc1 += inc1; }
    // 5-6: xs(1) -> slot 1
    { char* ld = pool + 1 * 8192 + w * 2048; dma16(gsrc0, ld); dma16(gsrc1, ld + 1024); gsrc0 += inc0; gsrc1 += inc1; }
    // 7-8: W1(0) -> slot 0
    { char* ld = pool + W1R0 + 0 * 8192 + w * 2048; dma16(gsW, ld); dma16(gsW + 1024, ld + 1024); }
    // 9-10: xs(2) -> slot 2
    { char* ld = pool + 2 * 8192 + w * 2048; dma16(gsrc0, ld); dma16(gsrc1, ld + 1024); gsrc0 += inc0; gsrc1 += inc1; }
    // 11-12: W1(1) -> slot 1
    { const char* gs1 = w1g + 8192 + w * 2048 + l * 16;
      char* ld = pool + W1R0 + 1 * 8192 + w * 2048; dma16(gs1, ld); dma16(gs1 + 1024, ld + 1024); }
    // 13-14: xs(3) -> slot 3
    { char* ld = pool + 3 * 8192 + w * 2048; dma16(gsrc0, ld); dma16(gsrc1, ld + 1024); gsrc0 += inc0; gsrc1 += inc1; }
    // gsrc now points at xs(4): period 0 issues it.
  }
  // completes #1-6 (W1 dummy, xs0, xs1); leaves 8 in flight. + h-zero visible.
  asm volatile("s_waitcnt vmcnt(8) lgkmcnt(0)\n\ts_barrier" ::: "memory");

  // pre-xproj(0) -> XPA (registers)
  {
    const char* xb = pool + 0 * 8192;
    float4 y0 = *(const float4*)(xb + offx0), y1 = *(const float4*)(xb + offx1);
    float4 y2 = *(const float4*)(xb + offx2), y3 = *(const float4*)(xb + offx3);
    float4 y4 = *(const float4*)(xb + offx4), y5 = *(const float4*)(xb + offx5);
    float4 y6 = *(const float4*)(xb + offx6), y7 = *(const float4*)(xb + offx7);
    bf16x8 ax0 = cvt8(y0, y1), ax1 = cvt8(y2, y3), ax2 = cvt8(y4, y5), ax3 = cvt8(y6, y7);
#pragma unroll
    for (int g = 0; g < 4; ++g) {
      f32x4 accg = {bias4[g], bias4[g], bias4[g], bias4[g]};
      accg = MFMA16(ax0, bwx[g][0], accg, 0, 0, 0);
      accg = MFMA16(ax1, bwx[g][1], accg, 0, 0, 0);
      accg = MFMA16(ax2, bwx[g][2], accg, 0, 0, 0);
      accg = MFMA16(ax3, bwx[g][3], accg, 0, 0, 0);
      XPA[g] = accg;
    }
  }

  // ---- main loop: 256 periods, unrolled x8, XPA/XPB alternate ----
#pragma unroll 1
  for (int pp = 0; pp < TT; pp += 8) {
    PERIOD(pp + 0, XPA, XPB) PERIOD(pp + 1, XPB, XPA)
    PERIOD(pp + 2, XPA, XPB) PERIOD(pp + 3, XPB, XPA)
    PERIOD(pp + 4, XPA, XPB) PERIOD(pp + 5, XPB, XPA)
    PERIOD(pp + 6, XPA, XPB) PERIOD(pp + 7, XPB, XPA)
  }

  __syncthreads();   // drains remaining in-flight DMAs before aliasing xs as W2

  // stage W2 into the dead xs region
  {
    float* w2l = (float*)pool;
    for (int i = tid; i < 4096; i += 256) w2l[i] = W2[i];
  }

  {
    // W1 tail: wacc += h(255) x W1block(255)   (h(255) in parity-0; W1(255) in slot 3)
    const char* hb = pool + HB0;
    bf16x8 at0 = *(const bf16x8*)(hb + row16 * 128 + (((0 + kg) << 4) ^ swz));
    bf16x8 at1 = *(const bf16x8*)(hb + row16 * 128 + (((4 + kg) << 4) ^ swz));
    const char* wbp = pool + W1R0 + 3 * 8192 + w * 2048 + l * 16;
    bf16x8 ba = *(const bf16x8*)(wbp);
    bf16x8 bb = *(const bf16x8*)(wbp + 1024);
    wacc = MFMA16(at0, ba, wacc, 0, 0, 0);
    wacc = MFMA16(at1, bb, wacc, 0, 0, 0);
    const float bv = b1[kcol];
    float* mlpa = (float*)(pool + MA0);
#pragma unroll
    for (int jj = 0; jj < 4; ++jj) {
      const int row = kg * 4 + jj;
      mlpa[row * 65 + kcol] = fmaxf(wacc[jj] + bv, 0.f);
      out[C_OFF + (size_t)(b0 + row) * HH + kcol] = cacc[jj];
      uint32_t hu = *(const uint16_t*)(hb + row * 128 +
                    (((kcol >> 3) << 4) ^ ((row & 7) << 4)) + (kcol & 7) * 2);
      union { uint32_t u; float f; } cv_; cv_.u = hu << 16;
      out[H_OFF + (size_t)(b0 + row) * HH + kcol] = cv_.f;
    }
  }
  __syncthreads();
  {  // MLP layer 2: 16x64 outputs
    const float* mlpa = (const float*)(pool + MA0);
    const float* w2l  = (const float*)pool;
    float* mlpb = (float*)(pool + MB0);
    const int b = tid >> 4, j0 = tid & 15;
    float s0 = b2[j0], s1 = b2[j0 + 16], s2 = b2[j0 + 32], s3 = b2[j0 + 48];
#pragma unroll 8
    for (int k = 0; k < 64; ++k) {
      const float av = mlpa[b * 65 + k];
      s0 += av * w2l[k * 64 + j0];
      s1 += av * w2l[k * 64 + j0 + 16];
      s2 += av * w2l[k * 64 + j0 + 32];
      s3 += av * w2l[k * 64 + j0 + 48];
    }
    mlpb[b * 65 + j0]      = fmaxf(s0, 0.f);
    mlpb[b * 65 + j0 + 16] = fmaxf(s1, 0.f);
    mlpb[b * 65 + j0 + 32] = fmaxf(s2, 0.f);
    mlpb[b * 65 + j0 + 48] = fmaxf(s3, 0.f);
  }
  __syncthreads();
  if (tid < 128) {  // MLP layer 3: 16x8 outputs
    const float* mlpb = (const float*)(pool + MB0);
    const int b = tid >> 3, jj = tid & 7;
    float s = b3[jj];
#pragma unroll 8
    for (int k = 0; k < 64; ++k) s += mlpb[b * 65 + k] * W3[(size_t)k * 8 + jj];
    out[(size_t)(b0 + b) * 8 + jj] = s;
  }
}

// ---------------- fallback (R2 kernel, used only if ws_size too small) ----------------
__global__ __launch_bounds__(256, 1) void actor_fused_fb(
    const float* __restrict__ x,  const float* __restrict__ pa,
    const float* __restrict__ Wx, const float* __restrict__ Wh,
    const float* __restrict__ bg, const float* __restrict__ W1,
    const float* __restrict__ b1, const float* __restrict__ W2,
    const float* __restrict__ b2, const float* __restrict__ W3,
    const float* __restrict__ b3, float* __restrict__ out)
{
  __shared__ __align__(16) uint16_t xs_lds[2][BB * 128];
  __shared__ __align__(16) uint16_t h_lds[2][BB * HH];
  __shared__ float w2_lds[64 * 64];
  __shared__ float mlp_a[BB * 65];
  __shared__ float mlp_b[BB * 65];

  const int tid = threadIdx.x, w = tid >> 6, l = tid & 63;
  const int row16 = l & 15, kg = l >> 4;
  const int b0 = blockIdx.x * BB, swz = (row16 & 7) << 4;

  bf16x8 bwx[4][4], bwh[4][2];
  float bias4[4];
#pragma unroll
  for (int g = 0; g < 4; ++g) {
    const int col = g * 64 + w * 16 + row16;
    bias4[g] = bg[col];
#pragma unroll
    for (int kf = 0; kf < 4; ++kf)
#pragma unroll
      for (int j = 0; j < 8; ++j)
        bwx[g][kf][j] = (short)f2bf(Wx[(size_t)(kf * 32 + kg * 8 + j) * GG + col]);
#pragma unroll
    for (int kf = 0; kf < 2; ++kf)
#pragma unroll
      for (int j = 0; j < 8; ++j)
        bwh[g][kf][j] = (short)f2bf(Wh[(size_t)(kf * 32 + kg * 8 + j) * GG + col]);
  }
  for (int i = tid; i < 64 * 64; i += 256) w2_lds[i] = W2[i];
  reinterpret_cast<uint64_t*>(&h_lds[0][0])[tid] = 0ull;

  const int srow = tid >> 4, li = tid & 15;
  const int st_byte = srow * 256 + ((li << 4) ^ ((srow & 7) << 4));
  {
    const size_t base = (size_t)(b0 + srow) * TT + 0;
    float4 fa, fb;
    if (li < 15) { fa = *(const float4*)(x + base * FF + li * 8);
                   fb = *(const float4*)(x + base * FF + li * 8 + 4); }
    else         { fa = *(const float4*)(x + base * FF + 120);
                   fb = *(const float4*)(pa + base * 4); }
    uint4 pk;
    pk.x = (uint32_t)f2bf(fa.x) | ((uint32_t)f2bf(fa.y) << 16);
    pk.y = (uint32_t)f2bf(fa.z) | ((uint32_t)f2bf(fa.w) << 16);
    pk.z = (uint32_t)f2bf(fb.x) | ((uint32_t)f2bf(fb.y) << 16);
    pk.w = (uint32_t)f2bf(fb.z) | ((uint32_t)f2bf(fb.w) << 16);
    *(uint4*)((char*)&xs_lds[0][0] + st_byte) = pk;
  }
  float4 pfa, pfb;
  {
    const size_t base = (size_t)(b0 + srow) * TT + 1;
    if (li < 15) { pfa = *(const float4*)(x + base * FF + li * 8);
                   pfb = *(const float4*)(x + base * FF + li * 8 + 4); }
    else         { pfa = *(const float4*)(x + base * FF + 120);
                   pfb = *(const float4*)(pa + base * 4); }
  }
  __syncthreads();

  f32x4 cacc = {0.f, 0.f, 0.f, 0.f};
  f32x4 wacc = {0.f, 0.f, 0.f, 0.f};
  int cur = 0;

  for (int t = 0; t < TT; ++t) {
    {
      uint4 pk;
      pk.x = (uint32_t)f2bf(pfa.x) | ((uint32_t)f2bf(pfa.y) << 16);
      pk.y = (uint32_t)f2bf(pfa.z) | ((uint32_t)f2bf(pfa.w) << 16);
      pk.z = (uint32_t)f2bf(pfb.x) | ((uint32_t)f2bf(pfb.y) << 16);
      pk.w = (uint32_t)f2bf(pfb.z) | ((uint32_t)f2bf(pfb.w) << 16);
      *(uint4*)((char*)&xs_lds[cur ^ 1][0] + st_byte) = pk;
    }
    {
      const int tp = (t + 2 < TT) ? (t + 2) : (TT - 1);
      const size_t base = (size_t)(b0 + srow) * TT + tp;
      if (li < 15) { pfa = *(const float4*)(x + base * FF + li * 8);
                     pfb = *(const float4*)(x + base * FF + li * 8 + 4); }
      else         { pfa = *(const float4*)(x + base * FF + 120);
                     pfb = *(const float4*)(pa + base * 4); }
    }
    bf16x8 bw1a, bw1b;
    if (t > 0) {
      const size_t r0 = (size_t)(t - 1) * 64 + kg * 8;
      const int c1w = w * 16 + row16;
#pragma unroll
      for (int j = 0; j < 8; ++j) {
        bw1a[j] = (short)f2bf(W1[(r0 + j) * 64 + c1w]);
        bw1b[j] = (short)f2bf(W1[(r0 + 32 + j) * 64 + c1w]);
      }
    }
    const char* xb = (const char*)&xs_lds[cur][0];
    const char* hb = (const char*)&h_lds[cur][0];
    bf16x8 ax0 = *(const bf16x8*)(xb + row16 * 256 + (((0 * 4 + kg) << 4) ^ swz));
    bf16x8 ax1 = *(const bf16x8*)(xb + row16 * 256 + (((1 * 4 + kg) << 4) ^ swz));
    bf16x8 ax2 = *(const bf16x8*)(xb + row16 * 256 + (((2 * 4 + kg) << 4) ^ swz));
    bf16x8 ax3 = *(const bf16x8*)(xb + row16 * 256 + (((3 * 4 + kg) << 4) ^ swz));
    bf16x8 ah0 = *(const bf16x8*)(hb + row16 * 128 + (((0 + kg) << 4) ^ swz));
    bf16x8 ah1 = *(const bf16x8*)(hb + row16 * 128 + (((4 + kg) << 4) ^ swz));

    f32x4 g0 = {bias4[0], bias4[0], bias4[0], bias4[0]};
    f32x4 g1 = {bias4[1], bias4[1], bias4[1], bias4[1]};
    f32x4 g2 = {bias4[2], bias4[2], bias4[2], bias4[2]};
    f32x4 g3 = {bias4[3], bias4[3], bias4[3], bias4[3]};
    g0 = MFMA16(ax0, bwx[0][0], g0, 0, 0, 0);
    g1 = MFMA16(ax0, bwx[1][0], g1, 0, 0, 0);
    g2 = MFMA16(ax0, bwx[2][0], g2, 0, 0, 0);
    g3 = MFMA16(ax0, bwx[3][0], g3, 0, 0, 0);
    g0 = MFMA16(ax1, bwx[0][1], g0, 0, 0, 0);
    g1 = MFMA16(ax1, bwx[1][1], g1, 0, 0, 0);
    g2 = MFMA16(ax1, bwx[2][1], g2, 0, 0, 0);
    g3 = MFMA16(ax1, bwx[3][1], g3, 0, 0, 0);
    g0 = MFMA16(ax2, bwx[0][2], g0, 0, 0, 0);
    g1 = MFMA16(ax2, bwx[1][2], g1, 0, 0, 0);
    g2 = MFMA16(ax2, bwx[2][2], g2, 0, 0, 0);
    g3 = MFMA16(ax2, bwx[3][2], g3, 0, 0, 0);
    g0 = MFMA16(ax3, bwx[0][3], g0, 0, 0, 0);
    g1 = MFMA16(ax3, bwx[1][3], g1, 0, 0, 0);
    g2 = MFMA16(ax3, bwx[2][3], g2, 0, 0, 0);
    g3 = MFMA16(ax3, bwx[3][3], g3, 0, 0, 0);
    g0 = MFMA16(ah0, bwh[0][0], g0, 0, 0, 0);
    g1 = MFMA16(ah0, bwh[1][0], g1, 0, 0, 0);
    g2 = MFMA16(ah0, bwh[2][0], g2, 0, 0, 0);
    g3 = MFMA16(ah0, bwh[3][0], g3, 0, 0, 0);
    g0 = MFMA16(ah1, bwh[0][1], g0, 0, 0, 0);
    g1 = MFMA16(ah1, bwh[1][1], g1, 0, 0, 0);
    g2 = MFMA16(ah1, bwh[2][1], g2, 0, 0, 0);
    g3 = MFMA16(ah1, bwh[3][1], g3, 0, 0, 0);
    if (t > 0) {
      wacc = MFMA16(ah0, bw1a, wacc, 0, 0, 0);
      wacc = MFMA16(ah1, bw1b, wacc, 0, 0, 0);
    }
    const int kcol = w * 16 + row16;
#pragma unroll
    for (int jj = 0; jj < 4; ++jj) {
      float i_ = fsig(g0[jj]);
      float f_ = fsig(g1[jj]);
      float gv = ftanh(g2[jj]);
      float o_ = fsig(g3[jj]);
      float cn = f_ * cacc[jj] + i_ * gv;
      cacc[jj] = cn;
      float hv = o_ * ftanh(cn);
      const int row = kg * 4 + jj;
      *(uint16_t*)((char*)&h_lds[cur ^ 1][0] + row * 128 +
                   (((kcol >> 3) << 4) ^ ((row & 7) << 4)) + (kcol & 7) * 2) = f2bf(hv);
      if (t == TT - 1) {
        out[C_OFF + (size_t)(b0 + row) * HH + kcol] = cn;
        out[H_OFF + (size_t)(b0 + row) * HH + kcol] = hv;
      }
    }
    __syncthreads();
    cur ^= 1;
  }
  {
    const char* hb = (const char*)&h_lds[cur][0];
    bf16x8 at0 = *(const bf16x8*)(hb + row16 * 128 + (((0 + kg) << 4) ^ swz));
    bf16x8 at1 = *(const bf16x8*)(hb + row16 * 128 + (((4 + kg) << 4) ^ swz));
    bf16x8 bw1a, bw1b;
    const size_t r0 = (size_t)(TT - 1) * 64 + kg * 8;
    const int c1w = w * 16 + row16;
#pragma unroll
    for (int j = 0; j < 8; ++j) {
      bw1a[j] = (short)f2bf(W1[(r0 + j) * 64 + c1w]);
      bw1b[j] = (short)f2bf(W1[(r0 + 32 + j) * 64 + c1w]);
    }
    wacc = MFMA16(at0, bw1a, wacc, 0, 0, 0);
    wacc = MFMA16(at1, bw1b, wacc, 0, 0, 0);
  }
  {
    const int kcol = w * 16 + row16;
    const float bv = b1[kcol];
#pragma unroll
    for (int jj = 0; jj < 4; ++jj)
      mlp_a[(kg * 4 + jj) * 65 + kcol] = fmaxf(wacc[jj] + bv, 0.f);
  }
  __syncthreads();
  {
    const int b = tid >> 4, j0 = tid & 15;
    float s0 = b2[j0], s1 = b2[j0 + 16], s2 = b2[j0 + 32], s3 = b2[j0 + 48];
#pragma unroll 8
    for (int k = 0; k < 64; ++k) {
      const float av = mlp_a[b * 65 + k];
      s0 += av * w2_lds[k * 64 + j0];
      s1 += av * w2_lds[k * 64 + j0 + 16];
      s2 += av * w2_lds[k * 64 + j0 + 32];
      s3 += av * w2_lds[k * 64 + j0 + 48];
    }
    mlp_b[b * 65 + j0]      = fmaxf(s0, 0.f);
    mlp_b[b * 65 + j0 + 16] = fmaxf(s1, 0.f);
    mlp_b[b * 65 + j0 + 32] = fmaxf(s2, 0.f);
    mlp_b[b * 65 + j0 + 48] = fmaxf(s3, 0.f);
  }
  __syncthreads();
  if (tid < 128) {
    const int b = tid >> 3, jj = tid & 7;
    float s = b3[jj];
#pragma unroll 8
    for (int k = 0; k < 64; ++k) s += mlp_b[b * 65 + k] * W3[(size_t)k * 8 + jj];
    out[(size_t)(b0 + b) * 8 + jj] = s;
  }
}

extern "C" void kernel_launch(void* const* d_in, const int* in_sizes, int n_in,
                              void* d_out, int out_size, void* d_ws, size_t ws_size,
                              hipStream_t stream) {
  const float* x  = (const float*)d_in[0];
  const float* pa = (const float*)d_in[1];
  const float* Wx = (const float*)d_in[2];
  const float* Wh = (const float*)d_in[3];
  const float* bg = (const float*)d_in[4];
  const float* W1 = (const float*)d_in[5];
  const float* b1 = (const float*)d_in[6];
  const float* W2 = (const float*)d_in[7];
  const float* b2 = (const float*)d_in[8];
  const float* W3 = (const float*)d_in[9];
  const float* b3 = (const float*)d_in[10];
  (void)in_sizes; (void)n_in; (void)out_size;

  if (ws_size >= WS_NEED) {
    uint16_t* wsp = (uint16_t*)d_ws;
    pack_weights<<<dim3(536), dim3(256), 0, stream>>>(Wx, Wh, W1, wsp);
    actor_merged<<<dim3(Bsz / BB), dim3(256), 0, stream>>>(
        x, pa, bg, wsp, b1, W2, b2, W3, b3, (float*)d_out);
  } else {
    actor_fused_fb<<<dim3(Bsz / BB), dim3(256), 0, stream>>>(
        x, pa, Wx, Wh, bg, W1, b1, W2, b2, W3, b3, (float*)d_out);
  }
}

// Round 12
// 182.100 us; speedup vs baseline: 2.9467x; 1.1534x over previous
//
#include <hip/hip_runtime.h>
#include <hip/hip_bf16.h>
#include <stdint.h>

static constexpr int Bsz = 1024;
static constexpr int TT  = 256;
static constexpr int FF  = 124;
static constexpr int HH  = 64;
static constexpr int GG  = 256;   // 4*H
static constexpr int BB  = 16;    // batch rows per block
static constexpr int C_OFF = Bsz * 8;
static constexpr int H_OFF = C_OFF + Bsz * HH;

// packed-weight workspace layout (uint16_t units)
static constexpr int WXH_U16 = 24 * 256 * 8;      // Wx/Wh frags
static constexpr int W1P_U16 = 256 * 4096;        // W1 frags, 256 blocks x 8KB
static constexpr size_t WS_NEED = (size_t)(WXH_U16 + W1P_U16) * 2;  // ~2.1 MB

// LDS pool layout (bytes)
static constexpr int XS0 = 0;        // 8 slots x 8192 (f32 xs, swizzled; W2 aliases after loop)
static constexpr int BX0 = 65536;    // 4 slots x 4096 (bf16 xs, MFMA-frag layout)
static constexpr int HB0 = 81920;    // 2 x 2048      (bf16 h, swizzled)
static constexpr int MA0 = 86016;    // 16*65*4
static constexpr int MB0 = 90176;    // 16*65*4
static constexpr int POOLSZ = 94336;

typedef __attribute__((ext_vector_type(8))) short bf16x8;
typedef __attribute__((ext_vector_type(4))) float f32x4;

#define MFMA16 __builtin_amdgcn_mfma_f32_16x16x32_bf16

__device__ __forceinline__ uint16_t f2bf(float x) {
  union { float f; uint32_t u; } v; v.f = x;
  return (uint16_t)((v.u + 0x7FFFu + ((v.u >> 16) & 1u)) >> 16);
}
__device__ __forceinline__ uint32_t cvtpk(float lo, float hi) {
  uint32_t r;
  asm("v_cvt_pk_bf16_f32 %0, %1, %2" : "=v"(r) : "v"(lo), "v"(hi));
  return r;
}
__device__ __forceinline__ uint16_t bf1(float x) { return (uint16_t)cvtpk(x, x); }
__device__ __forceinline__ float fsig(float x) {
  return __builtin_amdgcn_rcpf(1.0f + __builtin_amdgcn_exp2f(-1.4426950408889634f * x));
}
__device__ __forceinline__ float ftanh(float x) {
  float e = __builtin_amdgcn_exp2f(-2.8853900817779268f * x);
  return (1.0f - e) * __builtin_amdgcn_rcpf(1.0f + e);
}
__device__ __forceinline__ bf16x8 cvt8(float4 a, float4 b) {
  union { uint32_t u[4]; bf16x8 v; } r;
  r.u[0] = cvtpk(a.x, a.y); r.u[1] = cvtpk(a.z, a.w);
  r.u[2] = cvtpk(b.x, b.y); r.u[3] = cvtpk(b.z, b.w);
  return r.v;
}
__device__ __forceinline__ void dma16(const void* g, void* l) {
  __builtin_amdgcn_global_load_lds(
      (const __attribute__((address_space(1))) uint32_t*)g,
      (__attribute__((address_space(3))) uint32_t*)l, 16, 0, 0);
}

// ---------------- pre-pass: pack Wx/Wh/W1 into bf16 fragment order ----------------
__global__ __launch_bounds__(256) void pack_weights(
    const float* __restrict__ Wx, const float* __restrict__ Wh,
    const float* __restrict__ W1, uint16_t* __restrict__ wsp)
{
  const int c = blockIdx.x * 256 + threadIdx.x;
  uint16_t v[8];
  size_t dst;
  if (c < 6144) {                       // Wx/Wh frags: [f 0..23][tid 0..255][8]
    const int f = c >> 8, tid = c & 255;
    const int w = tid >> 6, l = tid & 63;
    const int kgl = (l >> 4) * 8, r16 = l & 15;
    if (f < 16) {
      const int g = f >> 2, kf = f & 3;
      const int col = g * 64 + w * 16 + r16;
#pragma unroll
      for (int j = 0; j < 8; ++j) v[j] = f2bf(Wx[(size_t)(kf * 32 + kgl + j) * GG + col]);
    } else {
      const int g = (f - 16) >> 1, kf = (f - 16) & 1;
      const int col = g * 64 + w * 16 + r16;
#pragma unroll
      for (int j = 0; j < 8; ++j) v[j] = f2bf(Wh[(size_t)(kf * 32 + kgl + j) * GG + col]);
    }
    dst = (size_t)c * 8;
  } else if (c < 6144 + 131072) {       // W1 frags: [t][w][half][l][8]
    const int cc = c - 6144;
    const int t = cc >> 9, r = cc & 511;
    const int w = r >> 7, half = (r >> 6) & 1, l = r & 63;
    const int row0 = t * 64 + half * 32 + (l >> 4) * 8;
    const int col = w * 16 + (l & 15);
#pragma unroll
    for (int j = 0; j < 8; ++j) v[j] = f2bf(W1[(size_t)(row0 + j) * 64 + col]);
    dst = (size_t)WXH_U16 + (size_t)cc * 8;
  } else return;
  uint4 pk;
  pk.x = (uint32_t)v[0] | ((uint32_t)v[1] << 16);
  pk.y = (uint32_t)v[2] | ((uint32_t)v[3] << 16);
  pk.z = (uint32_t)v[4] | ((uint32_t)v[5] << 16);
  pk.w = (uint32_t)v[6] | ((uint32_t)v[7] << 16);
  *(uint4*)(wsp + dst) = pk;
}

// ---------------- main kernel: 4 converter waves + 4 full consumers, 8 waves ----------------
// DMA invariants identical to R8: prologue stages xs(0..5) (12 DMAs); each
// converter period issues 2; vmcnt(6) at top of period t retires the pair
// delivering xs(t+2).  Converter at period t: cvt xs(t+2) f32 -> bxs slot
// (t+2)&3 (bf16, MFMA-frag layout).  Consumer at period t reads bxs slot t&3
// (converted at t-2 -> barrier-separated), computes gates = bias + xs@Wx + h@Wh
// itself, then the LSTM elementwise + W1 accumulation (R8-proven pieces).

#define PER_CVT(PRT, U) { \
  asm volatile("s_waitcnt vmcnt(6)" ::: "memory"); \
  if ((PRT) + 2 < TT) { \
    const char* xb = pool + (((U) + 2) & 7) * 8192; \
    float4 ya = *(const float4*)(xb + offxA); \
    float4 yb = *(const float4*)(xb + offxB); \
    bf16x8 bv = cvt8(ya, yb); \
    *(bf16x8*)(pool + BX0 + (((U) + 2) & 3) * 4096 + row16 * 256 + \
               (((pw * 4 + kg) << 4) ^ swz)) = bv; \
  } \
  { char* ld = pool + (((U) + 6) & 7) * 8192 + pw * 2048; \
    dma16(gsrc0, ld); dma16(gsrc1, ld + 1024); } \
  if ((PRT) + 7 < TT) { gsrc0 += inc0; gsrc1 += inc1; } }

#define PER_CONS(PRT, U) { \
  const uint16_t* w1p = wsp + (size_t)WXH_U16 + ((size_t)(PRT) * 512 + cs * 128 + l) * 8; \
  bf16x8 nw1a = *(const bf16x8*)(w1p); \
  bf16x8 nw1b = *(const bf16x8*)(w1p + 512); \
  const char* bx = pool + BX0 + ((U) & 3) * 4096; \
  bf16x8 ax0 = *(const bf16x8*)(bx + row16 * 256 + (((0 * 4 + kg) << 4) ^ swz)); \
  bf16x8 ax1 = *(const bf16x8*)(bx + row16 * 256 + (((1 * 4 + kg) << 4) ^ swz)); \
  bf16x8 ax2 = *(const bf16x8*)(bx + row16 * 256 + (((2 * 4 + kg) << 4) ^ swz)); \
  bf16x8 ax3 = *(const bf16x8*)(bx + row16 * 256 + (((3 * 4 + kg) << 4) ^ swz)); \
  const char* hb = pool + HB0 + ((U) & 1) * 2048; \
  bf16x8 ah0 = *(const bf16x8*)(hb + row16 * 128 + (((0 + kg) << 4) ^ swz)); \
  bf16x8 ah1 = *(const bf16x8*)(hb + row16 * 128 + (((4 + kg) << 4) ^ swz)); \
  f32x4 g0 = {bias4[0], bias4[0], bias4[0], bias4[0]}; \
  f32x4 g1 = {bias4[1], bias4[1], bias4[1], bias4[1]}; \
  f32x4 g2 = {bias4[2], bias4[2], bias4[2], bias4[2]}; \
  f32x4 g3 = {bias4[3], bias4[3], bias4[3], bias4[3]}; \
  g0 = MFMA16(ax0, bwx[0][0], g0, 0, 0, 0); \
  g1 = MFMA16(ax0, bwx[1][0], g1, 0, 0, 0); \
  g2 = MFMA16(ax0, bwx[2][0], g2, 0, 0, 0); \
  g3 = MFMA16(ax0, bwx[3][0], g3, 0, 0, 0); \
  g0 = MFMA16(ax1, bwx[0][1], g0, 0, 0, 0); \
  g1 = MFMA16(ax1, bwx[1][1], g1, 0, 0, 0); \
  g2 = MFMA16(ax1, bwx[2][1], g2, 0, 0, 0); \
  g3 = MFMA16(ax1, bwx[3][1], g3, 0, 0, 0); \
  g0 = MFMA16(ax2, bwx[0][2], g0, 0, 0, 0); \
  g1 = MFMA16(ax2, bwx[1][2], g1, 0, 0, 0); \
  g2 = MFMA16(ax2, bwx[2][2], g2, 0, 0, 0); \
  g3 = MFMA16(ax2, bwx[3][2], g3, 0, 0, 0); \
  g0 = MFMA16(ax3, bwx[0][3], g0, 0, 0, 0); \
  g1 = MFMA16(ax3, bwx[1][3], g1, 0, 0, 0); \
  g2 = MFMA16(ax3, bwx[2][3], g2, 0, 0, 0); \
  g3 = MFMA16(ax3, bwx[3][3], g3, 0, 0, 0); \
  g0 = MFMA16(ah0, bwh[0][0], g0, 0, 0, 0); \
  g1 = MFMA16(ah0, bwh[1][0], g1, 0, 0, 0); \
  g2 = MFMA16(ah0, bwh[2][0], g2, 0, 0, 0); \
  g3 = MFMA16(ah0, bwh[3][0], g3, 0, 0, 0); \
  g0 = MFMA16(ah1, bwh[0][1], g0, 0, 0, 0); \
  g1 = MFMA16(ah1, bwh[1][1], g1, 0, 0, 0); \
  g2 = MFMA16(ah1, bwh[2][1], g2, 0, 0, 0); \
  g3 = MFMA16(ah1, bwh[3][1], g3, 0, 0, 0); \
  wacc = MFMA16(ah0, cw1a, wacc, 0, 0, 0); \
  wacc = MFMA16(ah1, cw1b, wacc, 0, 0, 0); \
  cw1a = nw1a; cw1b = nw1b; \
  char* hw = pool + HB0 + (((U) & 1) ^ 1) * 2048; \
  _Pragma("unroll") \
  for (int jj = 0; jj < 4; ++jj) { \
    float i_ = fsig(g0[jj]); \
    float f_ = fsig(g1[jj]); \
    float gv = ftanh(g2[jj]); \
    float o_ = fsig(g3[jj]); \
    float cn = f_ * cacc[jj] + i_ * gv; \
    cacc[jj] = cn; \
    float hv = o_ * ftanh(cn); \
    const int row = kg * 4 + jj; \
    *(uint16_t*)(hw + row * 128 + (((kcol >> 3) << 4) ^ ((row & 7) << 4)) + (kcol & 7) * 2) = bf1(hv); \
  } }

#define PERIOD(PRT, U) { \
  if (w < 4) { PER_CONS(PRT, U) } else { PER_CVT(PRT, U) } \
  asm volatile("s_waitcnt lgkmcnt(0)\n\ts_barrier" ::: "memory"); }

// 512 threads = 8 waves = 2 waves/EU at 1 block/CU.  (512,2) -> VGPR cap 256
// (the ONLY declaration proven to unlock the allocator; R4-R7/R9-R10 all spilled
// under the default / (768,3) caps of 84-128).
__global__ __launch_bounds__(512, 2)
void actor_sx(
    const float* __restrict__ x,  const float* __restrict__ pa,
    const float* __restrict__ bg, const uint16_t* __restrict__ wsp,
    const float* __restrict__ b1, const float* __restrict__ W2,
    const float* __restrict__ b2, const float* __restrict__ W3,
    const float* __restrict__ b3, float* __restrict__ out)
{
  __shared__ __align__(16) char pool[POOLSZ];

  const int tid   = threadIdx.x;
  const int w     = tid >> 6;     // 0..3 consumers (gate-col slice), 4..7 converters
  const int cs    = w & 3;
  const int pw    = w & 3;
  const int l     = tid & 63;
  const int row16 = l & 15;
  const int kg    = l >> 4;
  const int b0    = blockIdx.x * BB;
  const int swz   = (row16 & 7) << 4;
  const int kcol  = cs * 16 + row16;

  if (w < 4) __builtin_amdgcn_s_setprio(1);

  // ---- role state ----
  bf16x8 bwx[4][4];     // consumers (loop-spanning)
  bf16x8 bwh[4][2];     // consumers
  float  bias4[4];      // consumers
  bf16x8 cw1a = {}, cw1b = {};
  float  cacc[4] = {0.f, 0.f, 0.f, 0.f};
  f32x4  wacc = {0.f, 0.f, 0.f, 0.f};

  // converter read offsets: this wave's K-quarter (kf = pw) of the f32 xs tile
  int offxA, offxB;
  {
    const int rb = row16 * 512, r7 = row16 & 7;
    offxA = rb + (((pw * 8 + kg * 2 + 0) ^ r7) << 4);
    offxB = rb + (((pw * 8 + kg * 2 + 1) ^ r7) << 4);
  }
  // xs DMA source pointers (per-lane swizzled global addresses) — R8-proven
  const char* gsrc0; const char* gsrc1; int inc0 = 0, inc1 = 0;
  {
#define GSRC(j, G, INC) { \
    const int d = pw * 2 + (j); \
    const int row = d * 2 + (l >> 5); \
    const int c_swz = l & 31; \
    const int c_or = c_swz ^ (row & 7); \
    const size_t rb_ = (size_t)(b0 + row) * TT; \
    if (c_or == 31) { G = (const char*)(pa + rb_ * 4); INC = 16; } \
    else { G = (const char*)(x + rb_ * FF + c_or * 4); INC = FF * 4; } }
    GSRC(0, gsrc0, inc0)
    GSRC(1, gsrc1, inc1)
#undef GSRC
  }

  if (w >= 4) {
    // prologue DMAs: xs(0..5) into slots 0..5 (12 issues, pair order per t)
#pragma unroll
    for (int s = 0; s < 6; ++s) {
      char* ld = pool + s * 8192 + pw * 2048;
      dma16(gsrc0, ld); dma16(gsrc1, ld + 1024);
      gsrc0 += inc0; gsrc1 += inc1;   // ends at t = 6
    }
  } else {
#pragma unroll
    for (int g = 0; g < 4; ++g) {
#pragma unroll
      for (int kf = 0; kf < 4; ++kf)
        bwx[g][kf] = *(const bf16x8*)(wsp + ((size_t)(g * 4 + kf) * 256 + cs * 64 + l) * 8);
#pragma unroll
      for (int kf = 0; kf < 2; ++kf)
        bwh[g][kf] = *(const bf16x8*)(wsp + ((size_t)(16 + g * 2 + kf) * 256 + cs * 64 + l) * 8);
      bias4[g] = bg[g * 64 + cs * 16 + row16];
    }
    const uint16_t* w1p = wsp + (size_t)WXH_U16 + ((size_t)cs * 128 + l) * 8;  // block 0
    cw1a = *(const bf16x8*)(w1p);
    cw1b = *(const bf16x8*)(w1p + 512);
  }
  if (tid < 256) ((uint64_t*)(pool + HB0))[tid] = 0ull;   // h_{-1} = 0 (parity 0)

  // ---- pre-periods: cvt xs(0) -> bxs0, cvt xs(1) -> bxs1 ----
#define PRE(TSTEP, VMC) \
  if (w >= 4) { \
    asm volatile("s_waitcnt vmcnt(" #VMC ")" ::: "memory"); \
    const char* xb = pool + (TSTEP) * 8192; \
    float4 ya = *(const float4*)(xb + offxA); \
    float4 yb = *(const float4*)(xb + offxB); \
    bf16x8 bv = cvt8(ya, yb); \
    *(bf16x8*)(pool + BX0 + (TSTEP) * 4096 + row16 * 256 + \
               (((pw * 4 + kg) << 4) ^ swz)) = bv; \
  } \
  asm volatile("s_waitcnt lgkmcnt(0)\n\ts_barrier" ::: "memory");

  PRE(0, 10)
  PRE(1, 8)
#undef PRE

  // ---- main loop: 256 periods, unrolled x8 (all ring indices are immediates) ----
#pragma unroll 1
  for (int pp = 0; pp < TT; pp += 8) {
    PERIOD(pp + 0, 0) PERIOD(pp + 1, 1) PERIOD(pp + 2, 2) PERIOD(pp + 3, 3)
    PERIOD(pp + 4, 4) PERIOD(pp + 5, 5) PERIOD(pp + 6, 6) PERIOD(pp + 7, 7)
  }

  __syncthreads();   // full drain (incl. in-flight DMAs) before aliasing xs as W2

  // stage W2 into the dead xs region
  {
    float* w2l = (float*)pool;
    for (int i = tid; i < 4096; i += 512) w2l[i] = W2[i];
  }

  if (w < 4) {
    // W1 tail: wacc += h(255) x W1block(255);  h(255) in parity-0 hbuf, cw1 = block 255
    const char* hb = pool + HB0;
    bf16x8 at0 = *(const bf16x8*)(hb + row16 * 128 + (((0 + kg) << 4) ^ swz));
    bf16x8 at1 = *(const bf16x8*)(hb + row16 * 128 + (((4 + kg) << 4) ^ swz));
    wacc = MFMA16(at0, cw1a, wacc, 0, 0, 0);
    wacc = MFMA16(at1, cw1b, wacc, 0, 0, 0);
    const float bv = b1[kcol];
    float* mlpa = (float*)(pool + MA0);
#pragma unroll
    for (int jj = 0; jj < 4; ++jj) {
      const int row = kg * 4 + jj;
      mlpa[row * 65 + kcol] = fmaxf(wacc[jj] + bv, 0.f);
      out[C_OFF + (size_t)(b0 + row) * HH + kcol] = cacc[jj];
      uint32_t hu = *(const uint16_t*)(hb + row * 128 +
                    (((kcol >> 3) << 4) ^ ((row & 7) << 4)) + (kcol & 7) * 2);
      union { uint32_t u; float f; } cv_; cv_.u = hu << 16;
      out[H_OFF + (size_t)(b0 + row) * HH + kcol] = cv_.f;
    }
  }
  __syncthreads();
  {  // MLP layer 2: 16x64 outputs, MA0 -> MB0
    const float* mlpa = (const float*)(pool + MA0);
    const float* w2l  = (const float*)pool;
    float* mlpb = (float*)(pool + MB0);
    const int b = tid >> 5, j0 = tid & 31;
    float s0 = b2[j0], s1 = b2[j0 + 32];
#pragma unroll 8
    for (int k = 0; k < 64; ++k) {
      const float av = mlpa[b * 65 + k];
      s0 += av * w2l[k * 64 + j0];
      s1 += av * w2l[k * 64 + j0 + 32];
    }
    mlpb[b * 65 + j0]      = fmaxf(s0, 0.f);
    mlpb[b * 65 + j0 + 32] = fmaxf(s1, 0.f);
  }
  __syncthreads();
  if (tid < 128) {  // MLP layer 3: 16x8 outputs
    const float* mlpb = (const float*)(pool + MB0);
    const int b = tid >> 3, jj = tid & 7;
    float s = b3[jj];
#pragma unroll 8
    for (int k = 0; k < 64; ++k) s += mlpb[b * 65 + k] * W3[(size_t)k * 8 + jj];
    out[(size_t)(b0 + b) * 8 + jj] = s;
  }
}

// ---------------- fallback (R2 kernel, used only if ws_size too small) ----------------
__global__ __launch_bounds__(256, 1) void actor_fused_fb(
    const float* __restrict__ x,  const float* __restrict__ pa,
    const float* __restrict__ Wx, const float* __restrict__ Wh,
    const float* __restrict__ bg, const float* __restrict__ W1,
    const float* __restrict__ b1, const float* __restrict__ W2,
    const float* __restrict__ b2, const float* __restrict__ W3,
    const float* __restrict__ b3, float* __restrict__ out)
{
  __shared__ __align__(16) uint16_t xs_lds[2][BB * 128];
  __shared__ __align__(16) uint16_t h_lds[2][BB * HH];
  __shared__ float w2_lds[64 * 64];
  __shared__ float mlp_a[BB * 65];
  __shared__ float mlp_b[BB * 65];

  const int tid = threadIdx.x, w = tid >> 6, l = tid & 63;
  const int row16 = l & 15, kg = l >> 4;
  const int b0 = blockIdx.x * BB, swz = (row16 & 7) << 4;

  bf16x8 bwx[4][4], bwh[4][2];
  float bias4[4];
#pragma unroll
  for (int g = 0; g < 4; ++g) {
    const int col = g * 64 + w * 16 + row16;
    bias4[g] = bg[col];
#pragma unroll
    for (int kf = 0; kf < 4; ++kf)
#pragma unroll
      for (int j = 0; j < 8; ++j)
        bwx[g][kf][j] = (short)f2bf(Wx[(size_t)(kf * 32 + kg * 8 + j) * GG + col]);
#pragma unroll
    for (int kf = 0; kf < 2; ++kf)
#pragma unroll
      for (int j = 0; j < 8; ++j)
        bwh[g][kf][j] = (short)f2bf(Wh[(size_t)(kf * 32 + kg * 8 + j) * GG + col]);
  }
  for (int i = tid; i < 64 * 64; i += 256) w2_lds[i] = W2[i];
  reinterpret_cast<uint64_t*>(&h_lds[0][0])[tid] = 0ull;

  const int srow = tid >> 4, li = tid & 15;
  const int st_byte = srow * 256 + ((li << 4) ^ ((srow & 7) << 4));
  {
    const size_t base = (size_t)(b0 + srow) * TT + 0;
    float4 fa, fb;
    if (li < 15) { fa = *(const float4*)(x + base * FF + li * 8);
                   fb = *(const float4*)(x + base * FF + li * 8 + 4); }
    else         { fa = *(const float4*)(x + base * FF + 120);
                   fb = *(const float4*)(pa + base * 4); }
    uint4 pk;
    pk.x = (uint32_t)f2bf(fa.x) | ((uint32_t)f2bf(fa.y) << 16);
    pk.y = (uint32_t)f2bf(fa.z) | ((uint32_t)f2bf(fa.w) << 16);
    pk.z = (uint32_t)f2bf(fb.x) | ((uint32_t)f2bf(fb.y) << 16);
    pk.w = (uint32_t)f2bf(fb.z) | ((uint32_t)f2bf(fb.w) << 16);
    *(uint4*)((char*)&xs_lds[0][0] + st_byte) = pk;
  }
  float4 pfa, pfb;
  {
    const size_t base = (size_t)(b0 + srow) * TT + 1;
    if (li < 15) { pfa = *(const float4*)(x + base * FF + li * 8);
                   pfb = *(const float4*)(x + base * FF + li * 8 + 4); }
    else         { pfa = *(const float4*)(x + base * FF + 120);
                   pfb = *(const float4*)(pa + base * 4); }
  }
  __syncthreads();

  f32x4 cacc = {0.f, 0.f, 0.f, 0.f};
  f32x4 wacc = {0.f, 0.f, 0.f, 0.f};
  int cur = 0;

  for (int t = 0; t < TT; ++t) {
    {
      uint4 pk;
      pk.x = (uint32_t)f2bf(pfa.x) | ((uint32_t)f2bf(pfa.y) << 16);
      pk.y = (uint32_t)f2bf(pfa.z) | ((uint32_t)f2bf(pfa.w) << 16);
      pk.z = (uint32_t)f2bf(pfb.x) | ((uint32_t)f2bf(pfb.y) << 16);
      pk.w = (uint32_t)f2bf(pfb.z) | ((uint32_t)f2bf(pfb.w) << 16);
      *(uint4*)((char*)&xs_lds[cur ^ 1][0] + st_byte) = pk;
    }
    {
      const int tp = (t + 2 < TT) ? (t + 2) : (TT - 1);
      const size_t base = (size_t)(b0 + srow) * TT + tp;
      if (li < 15) { pfa = *(const float4*)(x + base * FF + li * 8);
                     pfb = *(const float4*)(x + base * FF + li * 8 + 4); }
      else         { pfa = *(const float4*)(x + base * FF + 120);
                     pfb = *(const float4*)(pa + base * 4); }
    }
    bf16x8 bw1a, bw1b;
    if (t > 0) {
      const size_t r0 = (size_t)(t - 1) * 64 + kg * 8;
      const int c1w = w * 16 + row16;
#pragma unroll
      for (int j = 0; j < 8; ++j) {
        bw1a[j] = (short)f2bf(W1[(r0 + j) * 64 + c1w]);
        bw1b[j] = (short)f2bf(W1[(r0 + 32 + j) * 64 + c1w]);
      }
    }
    const char* xb = (const char*)&xs_lds[cur][0];
    const char* hb = (const char*)&h_lds[cur][0];
    bf16x8 ax0 = *(const bf16x8*)(xb + row16 * 256 + (((0 * 4 + kg) << 4) ^ swz));
    bf16x8 ax1 = *(const bf16x8*)(xb + row16 * 256 + (((1 * 4 + kg) << 4) ^ swz));
    bf16x8 ax2 = *(const bf16x8*)(xb + row16 * 256 + (((2 * 4 + kg) << 4) ^ swz));
    bf16x8 ax3 = *(const bf16x8*)(xb + row16 * 256 + (((3 * 4 + kg) << 4) ^ swz));
    bf16x8 ah0 = *(const bf16x8*)(hb + row16 * 128 + (((0 + kg) << 4) ^ swz));
    bf16x8 ah1 = *(const bf16x8*)(hb + row16 * 128 + (((4 + kg) << 4) ^ swz));

    f32x4 g0 = {bias4[0], bias4[0], bias4[0], bias4[0]};
    f32x4 g1 = {bias4[1], bias4[1], bias4[1], bias4[1]};
    f32x4 g2 = {bias4[2], bias4[2], bias4[2], bias4[2]};
    f32x4 g3 = {bias4[3], bias4[3], bias4[3], bias4[3]};
    g0 = MFMA16(ax0, bwx[0][0], g0, 0, 0, 0);
    g1 = MFMA16(ax0, bwx[1][0], g1, 0, 0, 0);
    g2 = MFMA16(ax0, bwx[2][0], g2, 0, 0, 0);
    g3 = MFMA16(ax0, bwx[3][0], g3, 0, 0, 0);
    g0 = MFMA16(ax1, bwx[0][1], g0, 0, 0, 0);
    g1 = MFMA16(ax1, bwx[1][1], g1, 0, 0, 0);
    g2 = MFMA16(ax1, bwx[2][1], g2, 0, 0, 0);
    g3 = MFMA16(ax1, bwx[3][1], g3, 0, 0, 0);
    g0 = MFMA16(ax2, bwx[0][2], g0, 0, 0, 0);
    g1 = MFMA16(ax2, bwx[1][2], g1, 0, 0, 0);
    g2 = MFMA16(ax2, bwx[2][2], g2, 0, 0, 0);
    g3 = MFMA16(ax2, bwx[3][2], g3, 0, 0, 0);
    g0 = MFMA16(ax3, bwx[0][3], g0, 0, 0, 0);
    g1 = MFMA16(ax3, bwx[1][3], g1, 0, 0, 0);
    g2 = MFMA16(ax3, bwx[2][3], g2, 0, 0, 0);
    g3 = MFMA16(ax3, bwx[3][3], g3, 0, 0, 0);
    g0 = MFMA16(ah0, bwh[0][0], g0, 0, 0, 0);
    g1 = MFMA16(ah0, bwh[1][0], g1, 0, 0, 0);
    g2 = MFMA16(ah0, bwh[2][0], g2, 0, 0, 0);
    g3 = MFMA16(ah0, bwh[3][0], g3, 0, 0, 0);
    g0 = MFMA16(ah1, bwh[0][1], g0, 0, 0, 0);
    g1 = MFMA16(ah1, bwh[1][1], g1, 0, 0, 0);
    g2 = MFMA16(ah1, bwh[2][1], g2, 0, 0, 0);
    g3 = MFMA16(ah1, bwh[3][1], g3, 0, 0, 0);
    if (t > 0) {
      wacc = MFMA16(ah0, bw1a, wacc, 0, 0, 0);
      wacc = MFMA16(ah1, bw1b, wacc, 0, 0, 0);
    }
    const int kcol = w * 16 + row16;
#pragma unroll
    for (int jj = 0; jj < 4; ++jj) {
      float i_ = fsig(g0[jj]);
      float f_ = fsig(g1[jj]);
      float gv = ftanh(g2[jj]);
      float o_ = fsig(g3[jj]);
      float cn = f_ * cacc[jj] + i_ * gv;
      cacc[jj] = cn;
      float hv = o_ * ftanh(cn);
      const int row = kg * 4 + jj;
      *(uint16_t*)((char*)&h_lds[cur ^ 1][0] + row * 128 +
                   (((kcol >> 3) << 4) ^ ((row & 7) << 4)) + (kcol & 7) * 2) = f2bf(hv);
      if (t == TT - 1) {
        out[C_OFF + (size_t)(b0 + row) * HH + kcol] = cn;
        out[H_OFF + (size_t)(b0 + row) * HH + kcol] = hv;
      }
    }
    __syncthreads();
    cur ^= 1;
  }
  {
    const char* hb = (const char*)&h_lds[cur][0];
    bf16x8 at0 = *(const bf16x8*)(hb + row16 * 128 + (((0 + kg) << 4) ^ swz));
    bf16x8 at1 = *(const bf16x8*)(hb + row16 * 128 + (((4 + kg) << 4) ^ swz));
    bf16x8 bw1a, bw1b;
    const size_t r0 = (size_t)(TT - 1) * 64 + kg * 8;
    const int c1w = w * 16 + row16;
#pragma unroll
    for (int j = 0; j < 8; ++j) {
      bw1a[j] = (short)f2bf(W1[(r0 + j) * 64 + c1w]);
      bw1b[j] = (short)f2bf(W1[(r0 + 32 + j) * 64 + c1w]);
    }
    wacc = MFMA16(at0, bw1a, wacc, 0, 0, 0);
    wacc = MFMA16(at1, bw1b, wacc, 0, 0, 0);
  }
  {
    const int kcol = w * 16 + row16;
    const float bv = b1[kcol];
#pragma unroll
    for (int jj = 0; jj < 4; ++jj)
      mlp_a[(kg * 4 + jj) * 65 + kcol] = fmaxf(wacc[jj] + bv, 0.f);
  }
  __syncthreads();
  {
    const int b = tid >> 4, j0 = tid & 15;
    float s0 = b2[j0], s1 = b2[j0 + 16], s2 = b2[j0 + 32], s3 = b2[j0 + 48];
#pragma unroll 8
    for (int k = 0; k < 64; ++k) {
      const float av = mlp_a[b * 65 + k];
      s0 += av * w2_lds[k * 64 + j0];
      s1 += av * w2_lds[k * 64 + j0 + 16];
      s2 += av * w2_lds[k * 64 + j0 + 32];
      s3 += av * w2_lds[k * 64 + j0 + 48];
    }
    mlp_b[b * 65 + j0]      = fmaxf(s0, 0.f);
    mlp_b[b * 65 + j0 + 16] = fmaxf(s1, 0.f);
    mlp_b[b * 65 + j0 + 32] = fmaxf(s2, 0.f);
    mlp_b[b * 65 + j0 + 48] = fmaxf(s3, 0.f);
  }
  __syncthreads();
  if (tid < 128) {
    const int b = tid >> 3, jj = tid & 7;
    float s = b3[jj];
#pragma unroll 8
    for (int k = 0; k < 64; ++k) s += mlp_b[b * 65 + k] * W3[(size_t)k * 8 + jj];
    out[(size_t)(b0 + b) * 8 + jj] = s;
  }
}

extern "C" void kernel_launch(void* const* d_in, const int* in_sizes, int n_in,
                              void* d_out, int out_size, void* d_ws, size_t ws_size,
                              hipStream_t stream) {
  const float* x  = (const float*)d_in[0];
  const float* pa = (const float*)d_in[1];
  const float* Wx = (const float*)d_in[2];
  const float* Wh = (const float*)d_in[3];
  const float* bg = (const float*)d_in[4];
  const float* W1 = (const float*)d_in[5];
  const float* b1 = (const float*)d_in[6];
  const float* W2 = (const float*)d_in[7];
  const float* b2 = (const float*)d_in[8];
  const float* W3 = (const float*)d_in[9];
  const float* b3 = (const float*)d_in[10];
  (void)in_sizes; (void)n_in; (void)out_size;

  if (ws_size >= WS_NEED) {
    uint16_t* wsp = (uint16_t*)d_ws;
    pack_weights<<<dim3(536), dim3(256), 0, stream>>>(Wx, Wh, W1, wsp);
    actor_sx<<<dim3(Bsz / BB), dim3(512), 0, stream>>>(
        x, pa, bg, wsp, b1, W2, b2, W3, b3, (float*)d_out);
  } else {
    actor_fused_fb<<<dim3(Bsz / BB), dim3(256), 0, stream>>>(
        x, pa, Wx, Wh, bg, W1, b1, W2, b2, W3, b3, (float*)d_out);
  }
}